// Round 2
// baseline (244.311 us; speedup 1.0000x reference)
//
#include <hip/hip_runtime.h>
#include <cmath>

#define NHID 64
#define NMONTH 16384
#define NAGENT 16
#define NROWS (NMONTH*NAGENT)   // 262144
#define NPROTO 24
#define TSEQ 32
#define NACT 12
#define EPS_P  1e-4f
#define EPS_BN 1e-5f
#define EPS_LN 1e-5f

typedef __attribute__((ext_vector_type(8))) short short8;
typedef __attribute__((ext_vector_type(4))) float f32x4;
typedef __attribute__((ext_vector_type(4))) unsigned short us4;
typedef __attribute__((ext_vector_type(8))) unsigned short us8;
typedef unsigned short ushort_t;

#define MFMA(a,b,c) __builtin_amdgcn_mfma_f32_16x16x32_bf16(a,b,c,0,0,0)
#define LPAD 68   // k6 LDS row stride (ushorts): 136B = 34 dwords -> 2-way (free)
#define LDSFENCE() asm volatile("s_waitcnt lgkmcnt(0)" ::: "memory")

// ---- ws layout (float offsets) ----
#define WS_TH     0        // [24][128] f32
#define WS_PV     3072     // [24][64]  f32
#define WS_PVSQ   4608     // [24] (pad 32)
#define WS_CTAB   4640     // [24][64]
#define WS_MID1   6176     // [64][64] f64 -> 8192 floats
#define WS_MID2   14368    // [64][64] f64
#define WS_BNSC   22560    // [64]
#define WS_BNSH   22624    // [64]
#define WS_WBF16  22688    // ushort region below
#define WO_FC1   0         // fc1w bf16 [64][64]
#define WO_GIH   4096      // gwih bf16 [192][64]
#define WO_GHH   16384     // gwhh bf16 [192][64]
#define WO_OUT   28672     // outw bf16 [16][64] (rows 12-15 zero)
#define WO_PV    29696     // pv bf16 [32][64] (rows 24-31 zero)
#define WO_CVX   31744     // convw[:, :64] bf16 [64][64]

__device__ __forceinline__ float sigf(float x){ return 1.0f/(1.0f+expf(-x)); }
__device__ __forceinline__ float fsig(float x){
  return __builtin_amdgcn_rcpf(1.f + __expf(-x));
}
__device__ __forceinline__ float ftanh(float x){
  return 1.f - 2.f*__builtin_amdgcn_rcpf(1.f + __expf(2.f*x));
}
__device__ __forceinline__ ushort_t f2bf(float f){
  unsigned u = __builtin_bit_cast(unsigned, f);
  u += 0x7FFFu + ((u>>16)&1u);           // round-to-nearest-even
  return (ushort_t)(u>>16);
}
__device__ __forceinline__ float bf2f(ushort_t b){
  return __builtin_bit_cast(float, ((unsigned)b)<<16);
}

// ---------------- K1: biLSTM over jieqi_info, 1 block per prototype ----------------
__global__ __launch_bounds__(256) void k1_lstm(
    const float* __restrict__ jq,
    const float* __restrict__ wif, const float* __restrict__ whf,
    const float* __restrict__ bif, const float* __restrict__ bhf,
    const float* __restrict__ wib, const float* __restrict__ bib, const float* __restrict__ bhb,
    float* __restrict__ th)
{
  const int p = blockIdx.x;
  const int j = threadIdx.x;
  __shared__ float hs[NHID];
  __shared__ float gs[4*NHID];
  float wh[NHID];
  #pragma unroll
  for (int k=0;k<NHID;k++) wh[k] = whf[j*NHID+k];
  const float wi0=wif[j*3], wi1=wif[j*3+1], wi2=wif[j*3+2];
  const float bj = bif[j]+bhf[j];
  float c = 0.f;
  if (j < NHID) hs[j] = 0.f;
  __syncthreads();
  for (int t=0;t<TSEQ;t++){
    const float x0=jq[(p*TSEQ+t)*3], x1=jq[(p*TSEQ+t)*3+1], x2=jq[(p*TSEQ+t)*3+2];
    float g = wi0*x0+wi1*x1+wi2*x2+bj;
    #pragma unroll
    for (int k=0;k<NHID;k++) g += wh[k]*hs[k];
    __syncthreads();
    gs[j] = g;
    __syncthreads();
    if (j < NHID){
      const float gi=gs[j], gf=gs[NHID+j], gg=gs[2*NHID+j], go=gs[3*NHID+j];
      c = sigf(gf)*c + sigf(gi)*tanhf(gg);
      hs[j] = sigf(go)*tanhf(c);
    }
    __syncthreads();
  }
  if (j < NHID) th[p*2*NHID + j] = hs[j];
  const float x0=jq[(p*TSEQ+TSEQ-1)*3], x1=jq[(p*TSEQ+TSEQ-1)*3+1], x2=jq[(p*TSEQ+TSEQ-1)*3+2];
  const float gb = wib[j*3]*x0 + wib[j*3+1]*x1 + wib[j*3+2]*x2 + bib[j]+bhb[j];
  __syncthreads();
  gs[j] = gb;
  __syncthreads();
  if (j < NHID){
    const float gi=gs[j], gg=gs[2*NHID+j], go=gs[3*NHID+j];
    const float cb = sigf(gi)*tanhf(gg);
    th[p*2*NHID + NHID + j] = sigf(go)*tanhf(cb);
  }
}

// ---------------- K2: prototype vectors, pv^2 sums, conv "chosen" table ----------------
__global__ __launch_bounds__(64) void k2_proto(
    const float* __restrict__ th, const float* __restrict__ fclw, const float* __restrict__ fclb,
    const float* __restrict__ projw, const float* __restrict__ convw, const float* __restrict__ convb,
    float* __restrict__ pv, float* __restrict__ pvsq, float* __restrict__ ctab)
{
  const int p = blockIdx.x, h = threadIdx.x;
  __shared__ float thr[2*NHID], t1[NHID], pvr[NHID];
  thr[h]      = th[p*2*NHID+h];
  thr[NHID+h] = th[p*2*NHID+NHID+h];
  __syncthreads();
  float acc = fclb[h];
  for (int k=0;k<2*NHID;k++) acc += thr[k]*fclw[h*2*NHID+k];
  t1[h] = fmaxf(acc,0.f);
  __syncthreads();
  float pvh = 0.f;
  for (int k=0;k<NHID;k++) pvh += t1[k]*projw[h*NHID+k];
  pv[p*NHID+h]=pvh; pvr[h]=pvh;
  __syncthreads();
  float ct = convb[h];
  for (int k=0;k<NHID;k++) ct += pvr[k]*convw[h*2*NHID+NHID+k];
  ctab[p*NHID+h]=ct;
  if (h==0){ float s=0.f; for (int k=0;k<NHID;k++) s+=pvr[k]*pvr[k]; pvsq[p]=s; }
}

// ---------------- K5w: weights -> bf16 ----------------
__global__ __launch_bounds__(256) void k5w_bf16(
    const float* __restrict__ fc1w, const float* __restrict__ gwih,
    const float* __restrict__ gwhh, const float* __restrict__ outw,
    const float* __restrict__ pvf, const float* __restrict__ convw,
    ushort_t* __restrict__ wb)
{
  const int t = threadIdx.x;
  for (int i=t;i<4096;i+=256)  wb[WO_FC1+i]=f2bf(fc1w[i]);
  for (int i=t;i<12288;i+=256){ wb[WO_GIH+i]=f2bf(gwih[i]); wb[WO_GHH+i]=f2bf(gwhh[i]); }
  for (int i=t;i<1024;i+=256)  wb[WO_OUT+i] = (i<768)? f2bf(outw[i]) : (ushort_t)0;
  for (int i=t;i<2048;i+=256)  wb[WO_PV+i]  = (i<1536)? f2bf(pvf[i]) : (ushort_t)0;
  for (int i=t;i<4096;i+=256)  wb[WO_CVX+i] = f2bf(convw[(i>>6)*128 + (i&63)]);
}

// ---------------- K3: ZERO-BARRIER wave-local MFMA distances+logits+argmax+conv ----------------
// All phases wave-local: each wave owns 16 rows. Staging, distances, logits,
// argmax, and conv (wave-row decomp, streamed conv-weight frags) never cross
// waves. In-wave LDS RAW ordered by explicit lgkmcnt fences.
__global__ __launch_bounds__(256) void k3_mfma(
    const float* __restrict__ inp, const int* __restrict__ month,
    const float* __restrict__ pvsq, const float* __restrict__ ctab,
    const float* __restrict__ lastw, const ushort_t* __restrict__ wb,
    float* __restrict__ out_logits, float* __restrict__ out_md,
    ushort_t* __restrict__ xgb, float* __restrict__ part1, float* __restrict__ part2)
{
  __shared__ ushort_t xl[64*72];     // x rows bf16 (wave-disjoint stripes)
  __shared__ float insql[64];        // fp32 row ||x||^2
  __shared__ float pal[64*26];       // prototype activations

  const int t = threadIdx.x;
  const int w = t>>6, lane = t&63;
  const int l15 = lane&15, kg = lane>>4, ko = kg*8;
  const int rbase = w*16;
  const size_t rowblk = (size_t)blockIdx.x*64;

  // ---- prefetch weight fragments + month ----
  const short8 pv0a = *reinterpret_cast<const short8*>(wb + WO_PV + l15*64 + ko);
  const short8 pv0b = *reinterpret_cast<const short8*>(wb + WO_PV + l15*64 + 32 + ko);
  const short8 pv1a = *reinterpret_cast<const short8*>(wb + WO_PV + (16+l15)*64 + ko);
  const short8 pv1b = *reinterpret_cast<const short8*>(wb + WO_PV + (16+l15)*64 + 32 + ko);
  const int mo = month[blockIdx.x*4 + w];
  const int season = ((mo+10)%12)/3;

  // ---- stage x -> bf16 LDS + fp32 insq (wave-local rows) ----
  {
    const int r = rbase + (lane>>2), cb = (lane&3)*16;
    const float* xrow = inp + (rowblk + r)*64 + cb;
    float s = 0.f;
    #pragma unroll
    for (int i=0;i<4;i++){
      const float4 xv = *reinterpret_cast<const float4*>(xrow + i*4);
      s += xv.x*xv.x + xv.y*xv.y + xv.z*xv.z + xv.w*xv.w;
      us4 y; y.x=f2bf(xv.x); y.y=f2bf(xv.y); y.z=f2bf(xv.z); y.w=f2bf(xv.w);
      *reinterpret_cast<us4*>(&xl[r*72+cb+i*4]) = y;
    }
    s += __shfl_xor(s,1,4);
    s += __shfl_xor(s,2,4);
    if ((lane&3)==0) insql[r] = s;
  }
  LDSFENCE();

  const int rowA = rbase + l15;
  const short8 ax0 = *reinterpret_cast<const short8*>(&xl[rowA*72+ko]);
  const short8 ax1 = *reinterpret_cast<const short8*>(&xl[rowA*72+32+ko]);

  // ---- distances: xp = X . PV^T (wave-row decomp) ----
  f32x4 d0={0.f,0.f,0.f,0.f}, d1=d0;
  d0 = MFMA(ax0, pv0a, d0);
  d0 = MFMA(ax1, pv0b, d0);
  d1 = MFMA(ax0, pv1a, d1);
  d1 = MFMA(ax1, pv1b, d1);
  {
    const float pq0 = pvsq[l15];
    const float pq1 = (l15<8)? pvsq[16+l15] : 0.f;
    #pragma unroll
    for (int j=0;j<4;j++){
      const int rloc = rbase + kg*4 + j;
      const float iq = insql[rloc];
      const float md0 = iq + pq0 - 2.f*d0[j];
      out_md[(rowblk+rloc)*24 + l15] = md0;
      pal[rloc*26 + l15] = __logf(md0+1.f) - __logf(md0+EPS_P);
      const float md1 = iq + pq1 - 2.f*d1[j];
      const float pa1 = __logf(md1+1.f) - __logf(md1+EPS_P);
      if (l15<8){
        out_md[(rowblk+rloc)*24 + 16+l15] = md1;
        pal[rloc*26 + 16+l15] = pa1;
      }
    }
  }
  LDSFENCE();   // pal ready for this wave

  // ---- logits (wave-local rows) ----
  {
    const int r2 = rbase + (lane>>2), c = lane&3;
    float lgv = 0.f;
    #pragma unroll
    for (int p=0;p<24;p++) lgv += pal[r2*26+p]*lastw[c*24+p];
    out_logits[(rowblk+r2)*4 + c] = lgv;
  }

  // ---- month argmax over 6 seasonal protos (all lanes; result in-register) ----
  int qsw;
  {
    float simv = -3.4e38f;
    const int j6 = lane & 7;
    if (j6 < 6){
      simv = 0.f;
      const int sp = season*6 + j6;
      #pragma unroll
      for (int i=0;i<16;i++) simv += pal[(rbase+i)*26 + sp];
    }
    int bidx = j6;
    { const float ov=__shfl_xor(simv,1,8); const int oi=__shfl_xor(bidx,1,8);
      if (ov>simv || (ov==simv && oi<bidx)){ simv=ov; bidx=oi; } }
    { const float ov=__shfl_xor(simv,2,8); const int oi=__shfl_xor(bidx,2,8);
      if (ov>simv || (ov==simv && oi<bidx)){ simv=ov; bidx=oi; } }
    { const float ov=__shfl_xor(simv,4,8); const int oi=__shfl_xor(bidx,4,8);
      if (ov>simv || (ov==simv && oi<bidx)){ simv=ov; bidx=oi; } }
    qsw = season*6 + bidx;
  }

  // ---- conv: wave-row decomp, streamed weight frags; per-wave BN partials ----
  ushort_t* xgblk = xgb + (size_t)blockIdx.x*8192;
  #pragma unroll
  for (int ct=0; ct<4; ct++){
    const int c = ct*16 + l15;
    const short8 cw0 = *reinterpret_cast<const short8*>(wb + WO_CVX + c*64 + ko);
    const short8 cw1 = *reinterpret_cast<const short8*>(wb + WO_CVX + c*64 + 32 + ko);
    f32x4 ac={0.f,0.f,0.f,0.f};
    ac = MFMA(ax0, cw0, ac);
    ac = MFMA(ax1, cw1, ac);
    const float cg = ctab[qsw*64 + c];
    float s1=0.f, s2=0.f;
    #pragma unroll
    for (int j=0;j<4;j++){
      const int rloc = rbase + kg*4 + j;
      const float v = ac[j] + cg;
      xgblk[rloc*64 + c] = f2bf(v);
      s1 += v; s2 += v*v;
    }
    s1 += __shfl_xor(s1,16); s1 += __shfl_xor(s1,32);
    s2 += __shfl_xor(s2,16); s2 += __shfl_xor(s2,32);
    if (kg==0){
      part1[((size_t)blockIdx.x*4 + w)*64 + c] = s1;
      part2[((size_t)blockIdx.x*4 + w)*64 + c] = s2;
    }
  }
}

// ---------------- K4b: partials [16384][64] -> mid [64][64] f64 ----------------
__global__ __launch_bounds__(64) void k4b_reduce(
    const float* __restrict__ part1, const float* __restrict__ part2,
    double* __restrict__ mid1, double* __restrict__ mid2)
{
  const int i = blockIdx.x, c = threadIdx.x;
  double s1=0.0, s2=0.0;
  for (int b=i*256; b<i*256+256; b++){
    s1 += (double)part1[b*64+c];
    s2 += (double)part2[b*64+c];
  }
  mid1[i*64+c]=s1; mid2[i*64+c]=s2;
}

// ---------------- K5: BN stats finalize ----------------
__global__ __launch_bounds__(64) void k5_finalize(
    const double* __restrict__ mid1, const double* __restrict__ mid2,
    const float* __restrict__ bng, const float* __restrict__ bnb,
    float* __restrict__ bnsc, float* __restrict__ bnsh)
{
  const int f = threadIdx.x;
  double s1=0.0, s2=0.0;
  for (int i=0;i<64;i++){ s1+=mid1[i*64+f]; s2+=mid2[i*64+f]; }
  const double mu = s1 / (double)NROWS;
  double var = s2/(double)NROWS - mu*mu;
  if (var < 0.0) var = 0.0;
  const float sc = bng[f] * (float)(1.0/sqrt(var + (double)EPS_BN));
  bnsc[f]=sc;
  bnsh[f]=bnb[f]-(float)mu*sc;
}

// ---------------- K6: ZERO-BARRIER wave-local  BN->fc1->LN->GRU->head ----------------
// Each wave owns 16 rows end-to-end. GRU + head use wave-row decomposition with
// streamed B-fragments from the L2-hot bf16 weight buffer, so the LN output and
// h never cross waves. In-wave LDS RAW ordered by explicit lgkmcnt fences.
__global__ __launch_bounds__(256) void k6_mfma(
    const ushort_t* __restrict__ xgb, const float* __restrict__ hidden,
    const float* __restrict__ bnsc, const float* __restrict__ bnsh,
    const float* __restrict__ fc1b, const float* __restrict__ lng, const float* __restrict__ lnb,
    const float* __restrict__ gbih, const float* __restrict__ gbhh,
    const float* __restrict__ outb,
    const ushort_t* __restrict__ wb,
    float* __restrict__ out_a, float* __restrict__ out_h)
{
  __shared__ ushort_t ybuf[64*LPAD];   // y -> ttl -> h (phased reuse, wave stripes)
  __shared__ ushort_t hidl[64*LPAD];
  const int t = threadIdx.x;
  const int lane = t & 63, w = t >> 6;
  const int l15 = lane & 15, kg = lane >> 4;
  const int ko = kg*8;
  const int rbase = w*16;

  // ---- prefetch fc1 weight frags (fly under staging) ----
  const short8 f0a = *reinterpret_cast<const short8*>(wb + WO_FC1 + ( 0+l15)*64 + ko);
  const short8 f0b = *reinterpret_cast<const short8*>(wb + WO_FC1 + ( 0+l15)*64 + 32 + ko);
  const short8 f1a = *reinterpret_cast<const short8*>(wb + WO_FC1 + (16+l15)*64 + ko);
  const short8 f1b = *reinterpret_cast<const short8*>(wb + WO_FC1 + (16+l15)*64 + 32 + ko);
  const short8 f2a = *reinterpret_cast<const short8*>(wb + WO_FC1 + (32+l15)*64 + ko);
  const short8 f2b = *reinterpret_cast<const short8*>(wb + WO_FC1 + (32+l15)*64 + 32 + ko);
  const short8 f3a = *reinterpret_cast<const short8*>(wb + WO_FC1 + (48+l15)*64 + ko);
  const short8 f3b = *reinterpret_cast<const short8*>(wb + WO_FC1 + (48+l15)*64 + 32 + ko);

  // ---- stage: BN+relu(x_bf16) and hidden -> bf16 LDS (wave-local rows) ----
  {
    const int r = rbase + (lane>>2), cb = (lane&3)*16;
    const ushort_t* xgp = xgb + (size_t)blockIdx.x*8192 + r*64 + cb;
    const us8 xv0 = *reinterpret_cast<const us8*>(xgp);
    const us8 xv1 = *reinterpret_cast<const us8*>(xgp+8);
    float xf[16];
    #pragma unroll
    for (int e=0;e<8;e++){ xf[e]=bf2f(xv0[e]); xf[8+e]=bf2f(xv1[e]); }
    const size_t g = ((size_t)blockIdx.x*64 + r)*64 + cb;
    #pragma unroll
    for (int i=0;i<4;i++){
      const float4 sc = *reinterpret_cast<const float4*>(bnsc + cb + i*4);
      const float4 sh = *reinterpret_cast<const float4*>(bnsh + cb + i*4);
      us4 y;
      y.x = f2bf(fmaxf(xf[4*i  ]*sc.x+sh.x,0.f));
      y.y = f2bf(fmaxf(xf[4*i+1]*sc.y+sh.y,0.f));
      y.z = f2bf(fmaxf(xf[4*i+2]*sc.z+sh.z,0.f));
      y.w = f2bf(fmaxf(xf[4*i+3]*sc.w+sh.w,0.f));
      *reinterpret_cast<us4*>(&ybuf[r*LPAD + cb + i*4]) = y;
      const float4 hv4 = *reinterpret_cast<const float4*>(hidden + g + i*4);
      us4 hb;
      hb.x=f2bf(hv4.x); hb.y=f2bf(hv4.y); hb.z=f2bf(hv4.z); hb.w=f2bf(hv4.w);
      *reinterpret_cast<us4*>(&hidl[r*LPAD + cb + i*4]) = hb;
    }
  }
  LDSFENCE();

  const int rowA = rbase + l15;
  const short8 ay0 = *reinterpret_cast<const short8*>(&ybuf[rowA*LPAD + ko]);
  const short8 ay1 = *reinterpret_cast<const short8*>(&ybuf[rowA*LPAD + 32 + ko]);
  const short8 bh0 = *reinterpret_cast<const short8*>(&hidl[rowA*LPAD + ko]);
  const short8 bh1 = *reinterpret_cast<const short8*>(&hidl[rowA*LPAD + 32 + ko]);

  // ---- fc1 (wave-row decomp, preloaded frags) ----
  f32x4 ac0={0.f,0.f,0.f,0.f}, ac1=ac0, ac2=ac0, ac3=ac0;
  ac0 = MFMA(ay0, f0a, ac0);  ac0 = MFMA(ay1, f0b, ac0);
  ac1 = MFMA(ay0, f1a, ac1);  ac1 = MFMA(ay1, f1b, ac1);
  ac2 = MFMA(ay0, f2a, ac2);  ac2 = MFMA(ay1, f2b, ac2);
  ac3 = MFMA(ay0, f3a, ac3);  ac3 = MFMA(ay1, f3b, ac3);
  {
    const float b0=fc1b[l15], b1=fc1b[16+l15], b2=fc1b[32+l15], b3=fc1b[48+l15];
    float tn0[4], tn1[4], tn2[4], tn3[4], mu[4], rs[4];
    #pragma unroll
    for (int j=0;j<4;j++){ tn0[j]=ac0[j]+b0; tn1[j]=ac1[j]+b1; tn2[j]=ac2[j]+b2; tn3[j]=ac3[j]+b3; }
    #pragma unroll
    for (int j=0;j<4;j++){
      float s = tn0[j]+tn1[j]+tn2[j]+tn3[j];
      s += __shfl_xor(s,1,16); s += __shfl_xor(s,2,16);
      s += __shfl_xor(s,4,16); s += __shfl_xor(s,8,16);
      mu[j] = s*(1.f/64.f);
    }
    #pragma unroll
    for (int j=0;j<4;j++){
      const float d0_=tn0[j]-mu[j], d1_=tn1[j]-mu[j], d2_=tn2[j]-mu[j], d3_=tn3[j]-mu[j];
      float v = d0_*d0_+d1_*d1_+d2_*d2_+d3_*d3_;
      v += __shfl_xor(v,1,16); v += __shfl_xor(v,2,16);
      v += __shfl_xor(v,4,16); v += __shfl_xor(v,8,16);
      rs[j] = 1.f/sqrtf(v*(1.f/64.f)+EPS_LN);
    }
    const float g0=lng[l15], g1=lng[16+l15], g2=lng[32+l15], g3=lng[48+l15];
    const float q0=lnb[l15], q1=lnb[16+l15], q2=lnb[32+l15], q3=lnb[48+l15];
    // LN result into own stripe (rows rbase+kg*4+j); antidep vs this wave's
    // ay reads is program order.
    #pragma unroll
    for (int j=0;j<4;j++){
      const int rr_ = rbase + kg*4 + j;
      ybuf[rr_*LPAD +      l15] = f2bf(fmaxf((tn0[j]-mu[j])*rs[j]*g0+q0, 0.f));
      ybuf[rr_*LPAD + 16 + l15] = f2bf(fmaxf((tn1[j]-mu[j])*rs[j]*g1+q1, 0.f));
      ybuf[rr_*LPAD + 32 + l15] = f2bf(fmaxf((tn2[j]-mu[j])*rs[j]*g2+q2, 0.f));
      ybuf[rr_*LPAD + 48 + l15] = f2bf(fmaxf((tn3[j]-mu[j])*rs[j]*g3+q3, 0.f));
    }
  }
  LDSFENCE();   // this wave's LN rows committed

  const short8 at0 = *reinterpret_cast<const short8*>(&ybuf[rowA*LPAD + ko]);
  const short8 at1 = *reinterpret_cast<const short8*>(&ybuf[rowA*LPAD + 32 + ko]);

  // ---- GRU: wave-row decomp, streamed weight frags per col-tile ----
  const ushort_t* gih = wb + WO_GIH;
  const ushort_t* ghh = wb + WO_GHH;
  #pragma unroll
  for (int ct=0; ct<4; ct++){
    const int c = ct*16 + l15;
    const short8 wr0 = *reinterpret_cast<const short8*>(gih + (      c)*64 + ko);
    const short8 wr1 = *reinterpret_cast<const short8*>(gih + (      c)*64 + 32 + ko);
    const short8 wz0 = *reinterpret_cast<const short8*>(gih + ( 64 + c)*64 + ko);
    const short8 wz1 = *reinterpret_cast<const short8*>(gih + ( 64 + c)*64 + 32 + ko);
    const short8 wn0 = *reinterpret_cast<const short8*>(gih + (128 + c)*64 + ko);
    const short8 wn1 = *reinterpret_cast<const short8*>(gih + (128 + c)*64 + 32 + ko);
    const short8 vr0 = *reinterpret_cast<const short8*>(ghh + (      c)*64 + ko);
    const short8 vr1 = *reinterpret_cast<const short8*>(ghh + (      c)*64 + 32 + ko);
    const short8 vz0 = *reinterpret_cast<const short8*>(ghh + ( 64 + c)*64 + ko);
    const short8 vz1 = *reinterpret_cast<const short8*>(ghh + ( 64 + c)*64 + 32 + ko);
    const short8 vn0 = *reinterpret_cast<const short8*>(ghh + (128 + c)*64 + ko);
    const short8 vn1 = *reinterpret_cast<const short8*>(ghh + (128 + c)*64 + 32 + ko);
    const float br  = gbih[c]      + gbhh[c];
    const float bz  = gbih[64+c]   + gbhh[64+c];
    const float bn_ = gbih[128+c];
    const float bhn = gbhh[128+c];
    f32x4 ar={0.f,0.f,0.f,0.f}, az=ar, an=ar, hn=ar;
    ar = MFMA(at0, wr0, ar);  ar = MFMA(at1, wr1, ar);
    ar = MFMA(bh0, vr0, ar);  ar = MFMA(bh1, vr1, ar);
    az = MFMA(at0, wz0, az);  az = MFMA(at1, wz1, az);
    az = MFMA(bh0, vz0, az);  az = MFMA(bh1, vz1, az);
    an = MFMA(at0, wn0, an);  an = MFMA(at1, wn1, an);
    hn = MFMA(bh0, vn0, hn);  hn = MFMA(bh1, vn1, hn);
    #pragma unroll
    for (int j=0;j<4;j++){
      const int rloc = rbase + kg*4 + j;
      const size_t rg_ = (size_t)blockIdx.x*64 + rloc;
      const float rrg = fsig(ar[j]+br);
      const float zzg = fsig(az[j]+bz);
      const float nng = ftanh(an[j]+bn_ + rrg*(hn[j]+bhn));
      const float hold = bf2f(hidl[rloc*LPAD + c]);
      const float hv = (1.f-zzg)*nng + zzg*hold;
      out_h[rg_*64 + c] = hv;
      ybuf[rloc*LPAD + c] = f2bf(hv);   // h into own stripe (ttl fully consumed)
    }
  }

  // ---- output head (wave-row decomp) ----
  const short8 ow0 = *reinterpret_cast<const short8*>(wb + WO_OUT + l15*64 + ko);
  const short8 ow1 = *reinterpret_cast<const short8*>(wb + WO_OUT + l15*64 + 32 + ko);
  const float ob = (l15 < 12) ? outb[l15] : 0.f;
  LDSFENCE();   // this wave's h rows committed

  const short8 av0 = *reinterpret_cast<const short8*>(&ybuf[rowA*LPAD + ko]);
  const short8 av1 = *reinterpret_cast<const short8*>(&ybuf[rowA*LPAD + 32 + ko]);
  f32x4 aa={0.f,0.f,0.f,0.f};
  aa = MFMA(av0, ow0, aa);
  aa = MFMA(av1, ow1, aa);
  if (l15 < 12){
    #pragma unroll
    for (int j=0;j<4;j++){
      const size_t rg_ = (size_t)blockIdx.x*64 + rbase + kg*4 + j;
      out_a[rg_*12 + l15] = aa[j] + ob;
    }
  }
}

extern "C" void kernel_launch(void* const* d_in, const int* in_sizes, int n_in,
                              void* d_out, int out_size, void* d_ws, size_t ws_size,
                              hipStream_t stream)
{
  (void)in_sizes; (void)n_in; (void)out_size; (void)ws_size;
  const float* inputs = (const float*)d_in[0];
  const float* hidden = (const float*)d_in[1];
  const int*   month  = (const int*)d_in[2];
  const float* jq     = (const float*)d_in[3];
  const float* wif    = (const float*)d_in[4];
  const float* whf    = (const float*)d_in[5];
  const float* bif    = (const float*)d_in[6];
  const float* bhf    = (const float*)d_in[7];
  const float* wib    = (const float*)d_in[8];
  const float* bib    = (const float*)d_in[10];
  const float* bhb    = (const float*)d_in[11];
  const float* fclw   = (const float*)d_in[12];
  const float* fclb   = (const float*)d_in[13];
  const float* projw  = (const float*)d_in[14];
  const float* convw  = (const float*)d_in[15];
  const float* convb  = (const float*)d_in[16];
  const float* bng    = (const float*)d_in[17];
  const float* bnb    = (const float*)d_in[18];
  const float* fc1w   = (const float*)d_in[19];
  const float* fc1b   = (const float*)d_in[20];
  const float* lng    = (const float*)d_in[21];
  const float* lnb    = (const float*)d_in[22];
  const float* gwih   = (const float*)d_in[23];
  const float* gwhh   = (const float*)d_in[24];
  const float* gbih   = (const float*)d_in[25];
  const float* gbhh   = (const float*)d_in[26];
  const float* outw   = (const float*)d_in[27];
  const float* outb   = (const float*)d_in[28];
  const float* lastw  = (const float*)d_in[29];

  float* ws  = (float*)d_ws;
  float* out = (float*)d_out;
  float* out_a  = out;
  float* out_h  = out + (size_t)NROWS*NACT;
  float* out_lg = out + (size_t)NROWS*(NACT+NHID);
  float* out_md = out + (size_t)NROWS*(NACT+NHID+4);
  ushort_t* wb = (ushort_t*)(ws + WS_WBF16);
  ushort_t* xgb = (ushort_t*)out_h;     // bf16 x_glb, block-local packed
  float* part1 = out_a;                 // [16384][64]
  float* part2 = out_a + (size_t)16384*64;

  hipLaunchKernelGGL(k1_lstm, dim3(NPROTO), dim3(256), 0, stream,
                     jq, wif, whf, bif, bhf, wib, bib, bhb, ws+WS_TH);
  hipLaunchKernelGGL(k2_proto, dim3(NPROTO), dim3(64), 0, stream,
                     ws+WS_TH, fclw, fclb, projw, convw, convb,
                     ws+WS_PV, ws+WS_PVSQ, ws+WS_CTAB);
  hipLaunchKernelGGL(k5w_bf16, dim3(1), dim3(256), 0, stream,
                     fc1w, gwih, gwhh, outw, ws+WS_PV, convw, wb);
  hipLaunchKernelGGL(k3_mfma, dim3(NROWS/64), dim3(256), 0, stream,
                     inputs, month, ws+WS_PVSQ, ws+WS_CTAB, lastw, wb,
                     out_lg, out_md, xgb, part1, part2);
  hipLaunchKernelGGL(k4b_reduce, dim3(64), dim3(64), 0, stream,
                     part1, part2, (double*)(ws+WS_MID1), (double*)(ws+WS_MID2));
  hipLaunchKernelGGL(k5_finalize, dim3(1), dim3(64), 0, stream,
                     (const double*)(ws+WS_MID1), (const double*)(ws+WS_MID2),
                     bng, bnb, ws+WS_BNSC, ws+WS_BNSH);
  hipLaunchKernelGGL(k6_mfma, dim3(NROWS/64), dim3(256), 0, stream,
                     xgb, hidden, ws+WS_BNSC, ws+WS_BNSH, fc1b, lng, lnb,
                     gbih, gbhh, outb, wb, out_a, out_h);
}

// Round 3
// 164.244 us; speedup vs baseline: 1.4875x; 1.4875x over previous
//
#include <hip/hip_runtime.h>
#include <cmath>

#define NHID 64
#define NMONTH 16384
#define NAGENT 16
#define NROWS (NMONTH*NAGENT)   // 262144
#define NPROTO 24
#define TSEQ 32
#define NACT 12
#define EPS_P  1e-4f
#define EPS_BN 1e-5f
#define EPS_LN 1e-5f

typedef __attribute__((ext_vector_type(8))) short short8;
typedef __attribute__((ext_vector_type(4))) float f32x4;
typedef __attribute__((ext_vector_type(4))) unsigned short us4;
typedef __attribute__((ext_vector_type(8))) unsigned short us8;
typedef __attribute__((ext_vector_type(4))) unsigned int uint4v;
typedef unsigned short ushort_t;

#define MFMA(a,b,c) __builtin_amdgcn_mfma_f32_16x16x32_bf16(a,b,c,0,0,0)
#define LPAD 68   // k6 LDS row stride (ushorts): 136B = 34 dwords -> 2-way (free)
#define LDSFENCE() asm volatile("s_waitcnt lgkmcnt(0)" ::: "memory")
#define LD8(P) (*reinterpret_cast<const short8*>(P))

// ---- ws layout (float offsets) ----
#define WS_TH     0        // [24][128] f32
#define WS_PV     3072     // [24][64]  f32
#define WS_PVSQ   4608     // [24] (pad 32)
#define WS_CTAB   4640     // [24][64]
#define WS_MID1   6176     // [64][64] f64 -> 8192 floats
#define WS_MID2   14368    // [64][64] f64
#define WS_BNSC   22560    // [64]
#define WS_BNSH   22624    // [64]
#define WS_WBF16  22688    // ushort region below
#define WO_FC1   0         // fc1w bf16 [64][64]
#define WO_GIH   4096      // gwih bf16 [192][64]
#define WO_GHH   16384     // gwhh bf16 [192][64]
#define WO_OUT   28672     // outw bf16 [16][64] (rows 12-15 zero)
#define WO_PV    29696     // pv bf16 [32][64] (rows 24-31 zero)
#define WO_CVX   31744     // convw[:, :64] bf16 [64][64]

__device__ __forceinline__ float sigf(float x){ return 1.0f/(1.0f+expf(-x)); }
__device__ __forceinline__ float fsig(float x){
  return __builtin_amdgcn_rcpf(1.f + __expf(-x));
}
__device__ __forceinline__ float ftanh(float x){
  return 1.f - 2.f*__builtin_amdgcn_rcpf(1.f + __expf(2.f*x));
}
__device__ __forceinline__ ushort_t f2bf(float f){
  unsigned u = __builtin_bit_cast(unsigned, f);
  u += 0x7FFFu + ((u>>16)&1u);           // round-to-nearest-even
  return (ushort_t)(u>>16);
}
__device__ __forceinline__ float bf2f(ushort_t b){
  return __builtin_bit_cast(float, ((unsigned)b)<<16);
}
// HW packed f32x2 -> bf16x2 (RNE), 1 VALU instr (no builtin on gfx950; m240)
__device__ __forceinline__ unsigned pk2bf(float a, float b){
  unsigned d;
  asm("v_cvt_pk_bf16_f32 %0, %1, %2" : "=v"(d) : "v"(a), "v"(b));
  return d;
}
// unpack 2 bf16 (one dword) -> 2 f32, 2 VALU
__device__ __forceinline__ void bf2x(unsigned u, float& a, float& b){
  a = __builtin_bit_cast(float, u<<16);
  b = __builtin_bit_cast(float, u & 0xFFFF0000u);
}

// ---------------- K1: biLSTM (blocks 0-23) + static weight->bf16 conv (blocks 24-27) ----------------
__global__ __launch_bounds__(256) void k1_lstm(
    const float* __restrict__ jq,
    const float* __restrict__ wif, const float* __restrict__ whf,
    const float* __restrict__ bif, const float* __restrict__ bhf,
    const float* __restrict__ wib, const float* __restrict__ bib, const float* __restrict__ bhb,
    const float* __restrict__ fc1w, const float* __restrict__ gwih,
    const float* __restrict__ gwhh, const float* __restrict__ outw,
    const float* __restrict__ convw, ushort_t* __restrict__ wb,
    float* __restrict__ th)
{
  __shared__ float hs[NHID];
  __shared__ float gs[4*NHID];
  if (blockIdx.x >= NPROTO){
    // static weight conversions (formerly k5w)
    const int tt = (blockIdx.x - NPROTO)*256 + threadIdx.x;   // 0..1023
    for (int i=tt;i<4096;i+=1024)  wb[WO_FC1+i]=f2bf(fc1w[i]);
    for (int i=tt;i<12288;i+=1024){ wb[WO_GIH+i]=f2bf(gwih[i]); wb[WO_GHH+i]=f2bf(gwhh[i]); }
    for (int i=tt;i<1024;i+=1024)  wb[WO_OUT+i] = (i<768)? f2bf(outw[i]) : (ushort_t)0;
    for (int i=tt;i<4096;i+=1024)  wb[WO_CVX+i] = f2bf(convw[(i>>6)*128 + (i&63)]);
    return;
  }
  const int p = blockIdx.x;
  const int j = threadIdx.x;
  float wh[NHID];
  #pragma unroll
  for (int k=0;k<NHID;k++) wh[k] = whf[j*NHID+k];
  const float wi0=wif[j*3], wi1=wif[j*3+1], wi2=wif[j*3+2];
  const float bj = bif[j]+bhf[j];
  float c = 0.f;
  if (j < NHID) hs[j] = 0.f;
  __syncthreads();
  for (int t=0;t<TSEQ;t++){
    const float x0=jq[(p*TSEQ+t)*3], x1=jq[(p*TSEQ+t)*3+1], x2=jq[(p*TSEQ+t)*3+2];
    float g = wi0*x0+wi1*x1+wi2*x2+bj;
    #pragma unroll
    for (int k=0;k<NHID;k++) g += wh[k]*hs[k];
    __syncthreads();
    gs[j] = g;
    __syncthreads();
    if (j < NHID){
      const float gi=gs[j], gf=gs[NHID+j], gg=gs[2*NHID+j], go=gs[3*NHID+j];
      c = sigf(gf)*c + sigf(gi)*tanhf(gg);
      hs[j] = sigf(go)*tanhf(c);
    }
    __syncthreads();
  }
  if (j < NHID) th[p*2*NHID + j] = hs[j];
  const float x0=jq[(p*TSEQ+TSEQ-1)*3], x1=jq[(p*TSEQ+TSEQ-1)*3+1], x2=jq[(p*TSEQ+TSEQ-1)*3+2];
  const float gb = wib[j*3]*x0 + wib[j*3+1]*x1 + wib[j*3+2]*x2 + bib[j]+bhb[j];
  __syncthreads();
  gs[j] = gb;
  __syncthreads();
  if (j < NHID){
    const float gi=gs[j], gg=gs[2*NHID+j], go=gs[3*NHID+j];
    const float cb = sigf(gi)*tanhf(gg);
    th[p*2*NHID + NHID + j] = sigf(go)*tanhf(cb);
  }
}

// ---------------- K2: prototype vectors, pv^2, conv "chosen" table, pv->bf16 ----------------
__global__ __launch_bounds__(64) void k2_proto(
    const float* __restrict__ th, const float* __restrict__ fclw, const float* __restrict__ fclb,
    const float* __restrict__ projw, const float* __restrict__ convw, const float* __restrict__ convb,
    float* __restrict__ pv, float* __restrict__ pvsq, float* __restrict__ ctab,
    ushort_t* __restrict__ wb)
{
  const int p = blockIdx.x, h = threadIdx.x;
  __shared__ float thr[2*NHID], t1[NHID], pvr[NHID];
  thr[h]      = th[p*2*NHID+h];
  thr[NHID+h] = th[p*2*NHID+NHID+h];
  __syncthreads();
  float acc = fclb[h];
  for (int k=0;k<2*NHID;k++) acc += thr[k]*fclw[h*2*NHID+k];
  t1[h] = fmaxf(acc,0.f);
  __syncthreads();
  float pvh = 0.f;
  for (int k=0;k<NHID;k++) pvh += t1[k]*projw[h*NHID+k];
  pv[p*NHID+h]=pvh; pvr[h]=pvh;
  wb[WO_PV + p*64 + h] = f2bf(pvh);
  if (p==0){
    #pragma unroll
    for (int r=24;r<32;r++) wb[WO_PV + r*64 + h] = (ushort_t)0;
  }
  __syncthreads();
  float ct = convb[h];
  for (int k=0;k<NHID;k++) ct += pvr[k]*convw[h*2*NHID+NHID+k];
  ctab[p*NHID+h]=ct;
  if (h==0){ float s=0.f; for (int k=0;k<NHID;k++) s+=pvr[k]*pvr[k]; pvsq[p]=s; }
}

// ---------------- K3: 2-tile MFMA distances+logits+argmax+conv + BN partials ----------------
// Block = 128 rows = 2 tiles of 64. Tile-1 inputs prefetched to regs during
// tile-0 compute. stage/distances/logits/argmax are wave-local (fences only);
// conv is the only cross-wave phase (1 barrier per tile + inter-tile guard).
#define K3_T1LOAD                                                             \
    _Pragma("unroll")                                                         \
    for (int i=0;i<4;i++)                                                     \
      xr1[i] = *reinterpret_cast<const float4*>(inp + (base + 64 + sr)*64 + scb + i*4);

#define K3_TILE(XR, SEASON, TOFF, PRE)                                        \
  {                                                                           \
    float ss = 0.f;                                                           \
    _Pragma("unroll")                                                         \
    for (int i=0;i<4;i++){                                                    \
      const float4 xv = XR[i];                                                \
      ss += xv.x*xv.x + xv.y*xv.y + xv.z*xv.z + xv.w*xv.w;                    \
      uint2 yy; yy.x = pk2bf(xv.x, xv.y); yy.y = pk2bf(xv.z, xv.w);           \
      *reinterpret_cast<uint2*>(&xl[sr*72 + scb + i*4]) = yy;                 \
    }                                                                         \
    ss += __shfl_xor(ss,1,4);  ss += __shfl_xor(ss,2,4);                      \
    if ((t&3)==0) insql[sr] = ss;                                             \
    LDSFENCE();                                                               \
    PRE                                                                       \
    const short8 ax0 = LD8(&xl[rowA*72+ko]);                                  \
    const short8 ax1 = LD8(&xl[rowA*72+32+ko]);                               \
    f32x4 d0={0.f,0.f,0.f,0.f}, d1=d0;                                        \
    d0 = MFMA(ax0, pv0a, d0);  d0 = MFMA(ax1, pv0b, d0);                      \
    d1 = MFMA(ax0, pv1a, d1);  d1 = MFMA(ax1, pv1b, d1);                      \
    _Pragma("unroll")                                                         \
    for (int j=0;j<4;j++){                                                    \
      const int rloc = rbase + kg*4 + j;                                      \
      const float iq = insql[rloc];                                           \
      const float md0 = iq + pq0 - 2.f*d0[j];                                 \
      out_md[(base + (TOFF) + rloc)*24 + l15] = md0;                          \
      pal[rloc*26 + l15] = __logf(md0+1.f) - __logf(md0+EPS_P);               \
      const float md1 = iq + pq1 - 2.f*d1[j];                                 \
      const float pa1 = __logf(md1+1.f) - __logf(md1+EPS_P);                  \
      if (l15<8){                                                             \
        out_md[(base + (TOFF) + rloc)*24 + 16+l15] = md1;                     \
        pal[rloc*26 + 16+l15] = pa1;                                          \
      }                                                                       \
    }                                                                         \
    LDSFENCE();                                                               \
    {                                                                         \
      const int r2 = rbase + (lane>>2), cc = lane&3;                          \
      float lgv = 0.f;                                                        \
      _Pragma("unroll")                                                       \
      for (int p=0;p<24;p++) lgv += pal[r2*26+p]*lastw[cc*24+p];              \
      out_logits[(base + (TOFF) + r2)*4 + cc] = lgv;                          \
    }                                                                         \
    int qsw;                                                                  \
    {                                                                         \
      float simv = -3.4e38f;                                                  \
      const int j6 = lane & 7;                                                \
      if (j6 < 6){                                                            \
        simv = 0.f;                                                           \
        const int sp = (SEASON)*6 + j6;                                       \
        _Pragma("unroll")                                                     \
        for (int i=0;i<16;i++) simv += pal[(rbase+i)*26 + sp];                \
      }                                                                       \
      int bidx = j6;                                                          \
      { const float ov=__shfl_xor(simv,1,8); const int oi=__shfl_xor(bidx,1,8); \
        if (ov>simv || (ov==simv && oi<bidx)){ simv=ov; bidx=oi; } }          \
      { const float ov=__shfl_xor(simv,2,8); const int oi=__shfl_xor(bidx,2,8); \
        if (ov>simv || (ov==simv && oi<bidx)){ simv=ov; bidx=oi; } }          \
      { const float ov=__shfl_xor(simv,4,8); const int oi=__shfl_xor(bidx,4,8); \
        if (ov>simv || (ov==simv && oi<bidx)){ simv=ov; bidx=oi; } }          \
      qsw = (SEASON)*6 + bidx;                                                \
    }                                                                         \
    __syncthreads();   /* all waves' xl ready for cross-wave conv */          \
    {                                                                         \
      const float cg = ctab[qsw*64 + gcol];                                   \
      ushort_t* xgo = xgb + (size_t)blockIdx.x*16384 + (TOFF)*64;             \
      _Pragma("unroll")                                                       \
      for (int rg=0; rg<4; rg++){                                             \
        const int ra = rg*16 + l15;                                           \
        const short8 bx0 = LD8(&xl[ra*72+ko]);                                \
        const short8 bx1 = LD8(&xl[ra*72+32+ko]);                             \
        f32x4 ac={0.f,0.f,0.f,0.f};                                           \
        ac = MFMA(bx0, cw0, ac);                                              \
        ac = MFMA(bx1, cw1, ac);                                              \
        _Pragma("unroll")                                                     \
        for (int j=0;j<4;j++){                                                \
          const int rloc = rg*16 + kg*4 + j;                                  \
          const float v = ac[j] + cg;                                         \
          xgo[rloc*64 + gcol] = f2bf(v);                                      \
          s1 += v; s2 += v*v;                                                 \
        }                                                                     \
      }                                                                       \
    }                                                                         \
  }

__global__ __launch_bounds__(256) void k3_mfma(
    const float* __restrict__ inp, const int* __restrict__ month,
    const float* __restrict__ pvsq, const float* __restrict__ ctab,
    const float* __restrict__ lastw, const ushort_t* __restrict__ wb,
    float* __restrict__ out_logits, float* __restrict__ out_md,
    ushort_t* __restrict__ xgb, float* __restrict__ part1, float* __restrict__ part2)
{
  __shared__ ushort_t xl[64*72];     // x rows bf16 (64-row tile, reused)
  __shared__ float insql[64];        // fp32 row ||x||^2
  __shared__ float pal[64*26];       // prototype activations (wave-local)

  const int t = threadIdx.x;
  const int w = t>>6, lane = t&63;
  const int l15 = lane&15, kg = lane>>4, ko = kg*8;
  const int gcol = w*16 + l15;
  const int rbase = w*16;
  const int rowA = rbase + l15;
  const int sr = t>>2, scb = (t&3)*16;
  const size_t base = (size_t)blockIdx.x*128;

  // ---- invariant prefetch ----
  const short8 pv0a = LD8(wb + WO_PV + l15*64 + ko);
  const short8 pv0b = LD8(wb + WO_PV + l15*64 + 32 + ko);
  const short8 pv1a = LD8(wb + WO_PV + (16+l15)*64 + ko);
  const short8 pv1b = LD8(wb + WO_PV + (16+l15)*64 + 32 + ko);
  const short8 cw0  = LD8(wb + WO_CVX + gcol*64 + ko);
  const short8 cw1  = LD8(wb + WO_CVX + gcol*64 + 32 + ko);
  const float pq0 = pvsq[l15];
  const float pq1 = (l15<8)? pvsq[16+l15] : 0.f;
  const int mo0 = month[blockIdx.x*8 + w];
  const int mo1 = month[blockIdx.x*8 + 4 + w];
  const int se0 = ((mo0+10)%12)/3;
  const int se1 = ((mo1+10)%12)/3;

  // ---- tile-0 input loads ----
  float4 xr0[4], xr1[4];
  #pragma unroll
  for (int i=0;i<4;i++)
    xr0[i] = *reinterpret_cast<const float4*>(inp + (base + sr)*64 + scb + i*4);

  float s1=0.f, s2=0.f;   // BN partials, accumulated over both tiles

  K3_TILE(xr0, se0, 0, K3_T1LOAD)
  __syncthreads();        // tile-0 conv reads done before tile-1 stage overwrites xl
  K3_TILE(xr1, se1, 64, )

  s1 += __shfl_xor(s1,16); s1 += __shfl_xor(s1,32);
  s2 += __shfl_xor(s2,16); s2 += __shfl_xor(s2,32);
  if (kg==0){
    part1[(size_t)blockIdx.x*64 + gcol] = s1;
    part2[(size_t)blockIdx.x*64 + gcol] = s2;
  }
}

// ---------------- K4b: partials [2048][64] -> mid [64][64] f64 ----------------
__global__ __launch_bounds__(64) void k4b_reduce(
    const float* __restrict__ part1, const float* __restrict__ part2,
    double* __restrict__ mid1, double* __restrict__ mid2)
{
  const int i = blockIdx.x, c = threadIdx.x;
  double s1=0.0, s2=0.0;
  for (int b=i*32; b<i*32+32; b++){
    s1 += (double)part1[b*64+c];
    s2 += (double)part2[b*64+c];
  }
  mid1[i*64+c]=s1; mid2[i*64+c]=s2;
}

// ---------------- K5: BN stats finalize ----------------
__global__ __launch_bounds__(64) void k5_finalize(
    const double* __restrict__ mid1, const double* __restrict__ mid2,
    const float* __restrict__ bng, const float* __restrict__ bnb,
    float* __restrict__ bnsc, float* __restrict__ bnsh)
{
  const int f = threadIdx.x;
  double s1=0.0, s2=0.0;
  for (int i=0;i<64;i++){ s1+=mid1[i*64+f]; s2+=mid2[i*64+f]; }
  const double mu = s1 / (double)NROWS;
  double var = s2/(double)NROWS - mu*mu;
  if (var < 0.0) var = 0.0;
  const float sc = bng[f] * (float)(1.0/sqrt(var + (double)EPS_BN));
  bnsc[f]=sc;
  bnsh[f]=bnb[f]-(float)mu*sc;
}

// ---------------- K6: 2-tile MFMA  BN->fc1->LN->GRU->head ----------------
// Block = 128 rows = 2 tiles. Tile-1 xgb+hidden prefetched to regs during
// tile-0 compute. stage/fc1/LN wave-local (fence only); GRU (col-tile,
// register-invariant weights) and head are the cross-wave phases.
#define K6_T1LOAD                                                             \
    xg1a = *reinterpret_cast<const us8*>(xgp1);                               \
    xg1b = *reinterpret_cast<const us8*>(xgp1+8);                             \
    _Pragma("unroll")                                                         \
    for (int i=0;i<4;i++)                                                     \
      hv1[i] = *reinterpret_cast<const float4*>(hidden + g1 + i*4);

#define K6_GRULOAD                                                            \
    wr0 = LD8(gih + (      gcol)*64 + ko); wr1 = LD8(gih + (      gcol)*64 + 32 + ko); \
    wz0 = LD8(gih + ( 64 + gcol)*64 + ko); wz1 = LD8(gih + ( 64 + gcol)*64 + 32 + ko); \
    wn0 = LD8(gih + (128 + gcol)*64 + ko); wn1 = LD8(gih + (128 + gcol)*64 + 32 + ko); \
    vr0 = LD8(ghh + (      gcol)*64 + ko); vr1 = LD8(ghh + (      gcol)*64 + 32 + ko); \
    vz0 = LD8(ghh + ( 64 + gcol)*64 + ko); vz1 = LD8(ghh + ( 64 + gcol)*64 + 32 + ko); \
    vn0 = LD8(ghh + (128 + gcol)*64 + ko); vn1 = LD8(ghh + (128 + gcol)*64 + 32 + ko); \
    br  = gbih[gcol]     + gbhh[gcol];                                        \
    bz  = gbih[64+gcol]  + gbhh[64+gcol];                                     \
    bn_ = gbih[128+gcol];                                                     \
    bhn = gbhh[128+gcol];

#define K6_TILE(XGA, XGB_, HV, TOFF, PRE1, PRE2, POST)                        \
  {                                                                           \
    {                                                                         \
      const uint4v xu0 = __builtin_bit_cast(uint4v, XGA);                     \
      const uint4v xu1 = __builtin_bit_cast(uint4v, XGB_);                    \
      float xf[16];                                                           \
      bf2x(xu0[0], xf[0],  xf[1]);  bf2x(xu0[1], xf[2],  xf[3]);              \
      bf2x(xu0[2], xf[4],  xf[5]);  bf2x(xu0[3], xf[6],  xf[7]);              \
      bf2x(xu1[0], xf[8],  xf[9]);  bf2x(xu1[1], xf[10], xf[11]);             \
      bf2x(xu1[2], xf[12], xf[13]); bf2x(xu1[3], xf[14], xf[15]);             \
      _Pragma("unroll")                                                       \
      for (int i=0;i<4;i++){                                                  \
        const float4 sc = *reinterpret_cast<const float4*>(bnsc + scb + i*4); \
        const float4 sh = *reinterpret_cast<const float4*>(bnsh + scb + i*4); \
        const float y0 = fmaxf(xf[4*i  ]*sc.x+sh.x, 0.f);                     \
        const float y1 = fmaxf(xf[4*i+1]*sc.y+sh.y, 0.f);                     \
        const float y2 = fmaxf(xf[4*i+2]*sc.z+sh.z, 0.f);                     \
        const float y3 = fmaxf(xf[4*i+3]*sc.w+sh.w, 0.f);                     \
        uint2 yy; yy.x = pk2bf(y0,y1); yy.y = pk2bf(y2,y3);                   \
        *reinterpret_cast<uint2*>(&ybuf[sr*LPAD + scb + i*4]) = yy;           \
        const float4 h4 = HV[i];                                              \
        uint2 hh; hh.x = pk2bf(h4.x,h4.y); hh.y = pk2bf(h4.z,h4.w);           \
        *reinterpret_cast<uint2*>(&hidl[sr*LPAD + scb + i*4]) = hh;           \
      }                                                                       \
    }                                                                         \
    LDSFENCE();                                                               \
    PRE1                                                                      \
    const short8 ay0 = LD8(&ybuf[rowA*LPAD + ko]);                            \
    const short8 ay1 = LD8(&ybuf[rowA*LPAD + 32 + ko]);                       \
    f32x4 ac0={0.f,0.f,0.f,0.f}, ac1=ac0, ac2=ac0, ac3=ac0;                   \
    ac0 = MFMA(ay0, f0a, ac0);  ac0 = MFMA(ay1, f0b, ac0);                    \
    ac1 = MFMA(ay0, f1a, ac1);  ac1 = MFMA(ay1, f1b, ac1);                    \
    ac2 = MFMA(ay0, f2a, ac2);  ac2 = MFMA(ay1, f2b, ac2);                    \
    ac3 = MFMA(ay0, f3a, ac3);  ac3 = MFMA(ay1, f3b, ac3);                    \
    {                                                                         \
      const float b0=fc1b[l15], b1=fc1b[16+l15], b2=fc1b[32+l15], b3=fc1b[48+l15]; \
      float tn0[4], tn1[4], tn2[4], tn3[4], mu[4], rs[4];                     \
      _Pragma("unroll")                                                       \
      for (int j=0;j<4;j++){ tn0[j]=ac0[j]+b0; tn1[j]=ac1[j]+b1; tn2[j]=ac2[j]+b2; tn3[j]=ac3[j]+b3; } \
      _Pragma("unroll")                                                       \
      for (int j=0;j<4;j++){                                                  \
        float s = tn0[j]+tn1[j]+tn2[j]+tn3[j];                                \
        s += __shfl_xor(s,1,16); s += __shfl_xor(s,2,16);                     \
        s += __shfl_xor(s,4,16); s += __shfl_xor(s,8,16);                     \
        mu[j] = s*(1.f/64.f);                                                 \
      }                                                                       \
      _Pragma("unroll")                                                       \
      for (int j=0;j<4;j++){                                                  \
        const float d0_=tn0[j]-mu[j], d1_=tn1[j]-mu[j], d2_=tn2[j]-mu[j], d3_=tn3[j]-mu[j]; \
        float v = d0_*d0_+d1_*d1_+d2_*d2_+d3_*d3_;                            \
        v += __shfl_xor(v,1,16); v += __shfl_xor(v,2,16);                     \
        v += __shfl_xor(v,4,16); v += __shfl_xor(v,8,16);                     \
        rs[j] = 1.f/sqrtf(v*(1.f/64.f)+EPS_LN);                               \
      }                                                                       \
      const float g0=lng[l15], g1=lng[16+l15], g2=lng[32+l15], g3=lng[48+l15]; \
      const float q0=lnb[l15], q1=lnb[16+l15], q2=lnb[32+l15], q3=lnb[48+l15]; \
      _Pragma("unroll")                                                       \
      for (int j=0;j<4;j++){                                                  \
        const int rr_ = rbase + kg*4 + j;                                     \
        ybuf[rr_*LPAD +      l15] = f2bf(fmaxf((tn0[j]-mu[j])*rs[j]*g0+q0, 0.f)); \
        ybuf[rr_*LPAD + 16 + l15] = f2bf(fmaxf((tn1[j]-mu[j])*rs[j]*g1+q1, 0.f)); \
        ybuf[rr_*LPAD + 32 + l15] = f2bf(fmaxf((tn2[j]-mu[j])*rs[j]*g2+q2, 0.f)); \
        ybuf[rr_*LPAD + 48 + l15] = f2bf(fmaxf((tn3[j]-mu[j])*rs[j]*g3+q3, 0.f)); \
      }                                                                       \
    }                                                                         \
    PRE2                                                                      \
    __syncthreads();   /* ttl + all waves' stage visible */                   \
    us4 hkeep[4];                                                             \
    _Pragma("unroll")                                                         \
    for (int rg=0; rg<4; rg++){                                               \
      const int ra = rg*16 + l15;                                             \
      const short8 at0 = LD8(&ybuf[ra*LPAD + ko]);                            \
      const short8 at1 = LD8(&ybuf[ra*LPAD + 32 + ko]);                       \
      const short8 bh0 = LD8(&hidl[ra*LPAD + ko]);                            \
      const short8 bh1 = LD8(&hidl[ra*LPAD + 32 + ko]);                       \
      f32x4 ar={0.f,0.f,0.f,0.f}, az=ar, an=ar, hn=ar;                        \
      ar = MFMA(at0, wr0, ar);  ar = MFMA(at1, wr1, ar);                      \
      ar = MFMA(bh0, vr0, ar);  ar = MFMA(bh1, vr1, ar);                      \
      az = MFMA(at0, wz0, az);  az = MFMA(at1, wz1, az);                      \
      az = MFMA(bh0, vz0, az);  az = MFMA(bh1, vz1, az);                      \
      an = MFMA(at0, wn0, an);  an = MFMA(at1, wn1, an);                      \
      hn = MFMA(bh0, vn0, hn);  hn = MFMA(bh1, vn1, hn);                      \
      us4 hb4;                                                                \
      _Pragma("unroll")                                                       \
      for (int j=0;j<4;j++){                                                  \
        const int rloc = rg*16 + kg*4 + j;                                    \
        const float rrg = fsig(ar[j]+br);                                     \
        const float zzg = fsig(az[j]+bz);                                     \
        const float nng = ftanh(an[j]+bn_ + rrg*(hn[j]+bhn));                 \
        const float hold = bf2f(hidl[rloc*LPAD + gcol]);                      \
        const float hv = (1.f-zzg)*nng + zzg*hold;                            \
        out_h[(base + (TOFF) + rloc)*64 + gcol] = hv;                         \
        hb4[j] = f2bf(hv);                                                    \
      }                                                                       \
      hkeep[rg] = hb4;                                                        \
    }                                                                         \
    __syncthreads();   /* all ttl/hidl reads done -> ybuf reusable */         \
    _Pragma("unroll")                                                         \
    for (int rg=0; rg<4; rg++){                                               \
      _Pragma("unroll")                                                       \
      for (int j=0;j<4;j++)                                                   \
        ybuf[(rg*16 + kg*4 + j)*LPAD + gcol] = hkeep[rg][j];                  \
    }                                                                         \
    __syncthreads();   /* hvl ready */                                        \
    {                                                                         \
      const short8 ow0 = LD8(wb + WO_OUT + l15*64 + ko);                      \
      const short8 ow1 = LD8(wb + WO_OUT + l15*64 + 32 + ko);                 \
      const float ob = (l15 < 12) ? outb[l15] : 0.f;                          \
      const short8 av0 = LD8(&ybuf[rowA*LPAD + ko]);                          \
      const short8 av1 = LD8(&ybuf[rowA*LPAD + 32 + ko]);                     \
      f32x4 aa={0.f,0.f,0.f,0.f};                                             \
      aa = MFMA(av0, ow0, aa);                                                \
      aa = MFMA(av1, ow1, aa);                                                \
      if (l15 < 12){                                                          \
        _Pragma("unroll")                                                     \
        for (int j=0;j<4;j++)                                                 \
          out_a[(base + (TOFF) + rbase + kg*4 + j)*12 + l15] = aa[j] + ob;    \
      }                                                                       \
    }                                                                         \
    POST                                                                      \
  }

__global__ __launch_bounds__(256) void k6_mfma(
    const ushort_t* __restrict__ xgb, const float* __restrict__ hidden,
    const float* __restrict__ bnsc, const float* __restrict__ bnsh,
    const float* __restrict__ fc1b, const float* __restrict__ lng, const float* __restrict__ lnb,
    const float* __restrict__ gbih, const float* __restrict__ gbhh,
    const float* __restrict__ outb,
    const ushort_t* __restrict__ wb,
    float* __restrict__ out_a, float* __restrict__ out_h)
{
  __shared__ ushort_t ybuf[64*LPAD];   // y -> ttl -> hvl (phased reuse)
  __shared__ ushort_t hidl[64*LPAD];
  const int t = threadIdx.x;
  const int lane = t & 63, w = t >> 6;
  const int l15 = lane & 15, kg = lane >> 4;
  const int ko = kg*8;
  const int rbase = w*16;
  const int rowA = rbase + l15;
  const int gcol = w*16 + l15;
  const int sr = t>>2, scb = (t&3)*16;
  const size_t base = (size_t)blockIdx.x*128;

  const ushort_t* gih = wb + WO_GIH;
  const ushort_t* ghh = wb + WO_GHH;

  // ---- fc1 weight frags (both tiles) ----
  const short8 f0a = LD8(wb + WO_FC1 + ( 0+l15)*64 + ko);
  const short8 f0b = LD8(wb + WO_FC1 + ( 0+l15)*64 + 32 + ko);
  const short8 f1a = LD8(wb + WO_FC1 + (16+l15)*64 + ko);
  const short8 f1b = LD8(wb + WO_FC1 + (16+l15)*64 + 32 + ko);
  const short8 f2a = LD8(wb + WO_FC1 + (32+l15)*64 + ko);
  const short8 f2b = LD8(wb + WO_FC1 + (32+l15)*64 + 32 + ko);
  const short8 f3a = LD8(wb + WO_FC1 + (48+l15)*64 + ko);
  const short8 f3b = LD8(wb + WO_FC1 + (48+l15)*64 + 32 + ko);

  // ---- GRU frags/biases: loaded in tile-0 (PRE2), live through tile-1 ----
  short8 wr0,wr1,wz0,wz1,wn0,wn1,vr0,vr1,vz0,vz1,vn0,vn1;
  float br,bz,bn_,bhn;

  // ---- tile-0 input loads ----
  const ushort_t* xgp0 = xgb + (size_t)blockIdx.x*16384 + sr*64 + scb;
  const ushort_t* xgp1 = xgp0 + 8192;
  const size_t g0 = (base + sr)*64 + scb;
  const size_t g1 = g0 + 64*64;
  us8 xg0a = *reinterpret_cast<const us8*>(xgp0);
  us8 xg0b = *reinterpret_cast<const us8*>(xgp0+8);
  us8 xg1a, xg1b;
  float4 hv0[4], hv1[4];
  #pragma unroll
  for (int i=0;i<4;i++)
    hv0[i] = *reinterpret_cast<const float4*>(hidden + g0 + i*4);

  K6_TILE(xg0a, xg0b, hv0, 0, K6_T1LOAD, K6_GRULOAD, __syncthreads();)
  K6_TILE(xg1a, xg1b, hv1, 64, , , )
}

extern "C" void kernel_launch(void* const* d_in, const int* in_sizes, int n_in,
                              void* d_out, int out_size, void* d_ws, size_t ws_size,
                              hipStream_t stream)
{
  (void)in_sizes; (void)n_in; (void)out_size; (void)ws_size;
  const float* inputs = (const float*)d_in[0];
  const float* hidden = (const float*)d_in[1];
  const int*   month  = (const int*)d_in[2];
  const float* jq     = (const float*)d_in[3];
  const float* wif    = (const float*)d_in[4];
  const float* whf    = (const float*)d_in[5];
  const float* bif    = (const float*)d_in[6];
  const float* bhf    = (const float*)d_in[7];
  const float* wib    = (const float*)d_in[8];
  const float* bib    = (const float*)d_in[10];
  const float* bhb    = (const float*)d_in[11];
  const float* fclw   = (const float*)d_in[12];
  const float* fclb   = (const float*)d_in[13];
  const float* projw  = (const float*)d_in[14];
  const float* convw  = (const float*)d_in[15];
  const float* convb  = (const float*)d_in[16];
  const float* bng    = (const float*)d_in[17];
  const float* bnb    = (const float*)d_in[18];
  const float* fc1w   = (const float*)d_in[19];
  const float* fc1b   = (const float*)d_in[20];
  const float* lng    = (const float*)d_in[21];
  const float* lnb    = (const float*)d_in[22];
  const float* gwih   = (const float*)d_in[23];
  const float* gwhh   = (const float*)d_in[24];
  const float* gbih   = (const float*)d_in[25];
  const float* gbhh   = (const float*)d_in[26];
  const float* outw   = (const float*)d_in[27];
  const float* outb   = (const float*)d_in[28];
  const float* lastw  = (const float*)d_in[29];

  float* ws  = (float*)d_ws;
  float* out = (float*)d_out;
  float* out_a  = out;
  float* out_h  = out + (size_t)NROWS*NACT;
  float* out_lg = out + (size_t)NROWS*(NACT+NHID);
  float* out_md = out + (size_t)NROWS*(NACT+NHID+4);
  ushort_t* wb = (ushort_t*)(ws + WS_WBF16);
  ushort_t* xgb = (ushort_t*)out_h;     // bf16 x_glb, block-local packed (128 rows/block)
  float* part1 = out_a;                 // [2048][64]
  float* part2 = out_a + (size_t)2048*64;

  hipLaunchKernelGGL(k1_lstm, dim3(NPROTO+4), dim3(256), 0, stream,
                     jq, wif, whf, bif, bhf, wib, bib, bhb,
                     fc1w, gwih, gwhh, outw, convw, wb, ws+WS_TH);
  hipLaunchKernelGGL(k2_proto, dim3(NPROTO), dim3(64), 0, stream,
                     ws+WS_TH, fclw, fclb, projw, convw, convb,
                     ws+WS_PV, ws+WS_PVSQ, ws+WS_CTAB, wb);
  hipLaunchKernelGGL(k3_mfma, dim3(NROWS/128), dim3(256), 0, stream,
                     inputs, month, ws+WS_PVSQ, ws+WS_CTAB, lastw, wb,
                     out_lg, out_md, xgb, part1, part2);
  hipLaunchKernelGGL(k4b_reduce, dim3(64), dim3(64), 0, stream,
                     part1, part2, (double*)(ws+WS_MID1), (double*)(ws+WS_MID2));
  hipLaunchKernelGGL(k5_finalize, dim3(1), dim3(64), 0, stream,
                     (const double*)(ws+WS_MID1), (const double*)(ws+WS_MID2),
                     bng, bnb, ws+WS_BNSC, ws+WS_BNSH);
  hipLaunchKernelGGL(k6_mfma, dim3(NROWS/128), dim3(256), 0, stream,
                     xgb, hidden, ws+WS_BNSC, ws+WS_BNSH, fc1b, lng, lnb,
                     gbih, gbhh, outb, wb, out_a, out_h);
}

// Round 4
// 145.327 us; speedup vs baseline: 1.6811x; 1.1302x over previous
//
#include <hip/hip_runtime.h>
#include <cmath>

#define NHID 64
#define NMONTH 16384
#define NAGENT 16
#define NROWS (NMONTH*NAGENT)   // 262144
#define NPROTO 24
#define TSEQ 32
#define NACT 12
#define EPS_P  1e-4f
#define EPS_BN 1e-5f
#define EPS_LN 1e-5f

typedef __attribute__((ext_vector_type(8))) short short8;
typedef __attribute__((ext_vector_type(4))) float f32x4;
typedef __attribute__((ext_vector_type(4))) unsigned short us4;
typedef __attribute__((ext_vector_type(8))) unsigned short us8;
typedef unsigned short ushort_t;

#define MFMA(a,b,c) __builtin_amdgcn_mfma_f32_16x16x32_bf16(a,b,c,0,0,0)
#define LPAD 68   // k6 LDS row stride (ushorts): 136B = 34 dwords -> 2-way (free)
#define LDSFENCE() asm volatile("s_waitcnt lgkmcnt(0)" ::: "memory")
#define LD8(P) (*reinterpret_cast<const short8*>(P))

// ---- ws layout (float offsets) ----
#define WS_TH     0        // [24][128] f32
#define WS_PV     3072     // [24][64]  f32
#define WS_PVSQ   4608     // [24] (pad 32)
#define WS_CTAB   4640     // [24][64]
#define WS_MID1   6176     // [64][64] f64 -> 8192 floats
#define WS_MID2   14368    // [64][64] f64
#define WS_BNSC   22560    // [64]
#define WS_BNSH   22624    // [64]
#define WS_WBF16  22688    // ushort region below
#define WO_FC1   0         // fc1w bf16 [64][64]
#define WO_GIH   4096      // gwih bf16 [192][64]
#define WO_GHH   16384     // gwhh bf16 [192][64]
#define WO_OUT   28672     // outw bf16 [16][64] (rows 12-15 zero)
#define WO_PV    29696     // pv bf16 [32][64] (rows 24-31 zero)
#define WO_CVX   31744     // convw[:, :64] bf16 [64][64]

__device__ __forceinline__ float sigf(float x){ return 1.0f/(1.0f+expf(-x)); }
__device__ __forceinline__ float fsig(float x){
  return __builtin_amdgcn_rcpf(1.f + __expf(-x));
}
__device__ __forceinline__ float ftanh(float x){
  return 1.f - 2.f*__builtin_amdgcn_rcpf(1.f + __expf(2.f*x));
}
__device__ __forceinline__ ushort_t f2bf(float f){
  unsigned u = __builtin_bit_cast(unsigned, f);
  u += 0x7FFFu + ((u>>16)&1u);           // round-to-nearest-even
  return (ushort_t)(u>>16);
}
__device__ __forceinline__ float bf2f(ushort_t b){
  return __builtin_bit_cast(float, ((unsigned)b)<<16);
}
// HW packed f32x2 -> bf16x2 (RNE), 1 VALU instr
__device__ __forceinline__ unsigned pk2bf(float a, float b){
  unsigned d;
  asm("v_cvt_pk_bf16_f32 %0, %1, %2" : "=v"(d) : "v"(a), "v"(b));
  return d;
}
// 1-instr scalar f32->bf16 (low half of cvt_pk)
__device__ __forceinline__ ushort_t f2bf_hw(float x){
  unsigned d;
  asm("v_cvt_pk_bf16_f32 %0, %1, %2" : "=v"(d) : "v"(x), "v"(x));
  return (ushort_t)d;
}

// ---------------- K1: biLSTM (blocks 0-23) + static weight->bf16 conv (blocks 24-27) ----------------
__global__ __launch_bounds__(256) void k1_lstm(
    const float* __restrict__ jq,
    const float* __restrict__ wif, const float* __restrict__ whf,
    const float* __restrict__ bif, const float* __restrict__ bhf,
    const float* __restrict__ wib, const float* __restrict__ bib, const float* __restrict__ bhb,
    const float* __restrict__ fc1w, const float* __restrict__ gwih,
    const float* __restrict__ gwhh, const float* __restrict__ outw,
    const float* __restrict__ convw, ushort_t* __restrict__ wb,
    float* __restrict__ th)
{
  __shared__ float hs[NHID];
  __shared__ float gs[4*NHID];
  if (blockIdx.x >= NPROTO){
    const int tt = (blockIdx.x - NPROTO)*256 + threadIdx.x;   // 0..1023
    for (int i=tt;i<4096;i+=1024)  wb[WO_FC1+i]=f2bf(fc1w[i]);
    for (int i=tt;i<12288;i+=1024){ wb[WO_GIH+i]=f2bf(gwih[i]); wb[WO_GHH+i]=f2bf(gwhh[i]); }
    for (int i=tt;i<1024;i+=1024)  wb[WO_OUT+i] = (i<768)? f2bf(outw[i]) : (ushort_t)0;
    for (int i=tt;i<4096;i+=1024)  wb[WO_CVX+i] = f2bf(convw[(i>>6)*128 + (i&63)]);
    return;
  }
  const int p = blockIdx.x;
  const int j = threadIdx.x;
  float wh[NHID];
  #pragma unroll
  for (int k=0;k<NHID;k++) wh[k] = whf[j*NHID+k];
  const float wi0=wif[j*3], wi1=wif[j*3+1], wi2=wif[j*3+2];
  const float bj = bif[j]+bhf[j];
  float c = 0.f;
  if (j < NHID) hs[j] = 0.f;
  __syncthreads();
  for (int t=0;t<TSEQ;t++){
    const float x0=jq[(p*TSEQ+t)*3], x1=jq[(p*TSEQ+t)*3+1], x2=jq[(p*TSEQ+t)*3+2];
    float g = wi0*x0+wi1*x1+wi2*x2+bj;
    #pragma unroll
    for (int k=0;k<NHID;k++) g += wh[k]*hs[k];
    __syncthreads();
    gs[j] = g;
    __syncthreads();
    if (j < NHID){
      const float gi=gs[j], gf=gs[NHID+j], gg=gs[2*NHID+j], go=gs[3*NHID+j];
      c = sigf(gf)*c + sigf(gi)*tanhf(gg);
      hs[j] = sigf(go)*tanhf(c);
    }
    __syncthreads();
  }
  if (j < NHID) th[p*2*NHID + j] = hs[j];
  const float x0=jq[(p*TSEQ+TSEQ-1)*3], x1=jq[(p*TSEQ+TSEQ-1)*3+1], x2=jq[(p*TSEQ+TSEQ-1)*3+2];
  const float gb = wib[j*3]*x0 + wib[j*3+1]*x1 + wib[j*3+2]*x2 + bib[j]+bhb[j];
  __syncthreads();
  gs[j] = gb;
  __syncthreads();
  if (j < NHID){
    const float gi=gs[j], gg=gs[2*NHID+j], go=gs[3*NHID+j];
    const float cb = sigf(gi)*tanhf(gg);
    th[p*2*NHID + NHID + j] = sigf(go)*tanhf(cb);
  }
}

// ---------------- K2: prototype vectors, pv^2, conv "chosen" table, pv->bf16 ----------------
__global__ __launch_bounds__(64) void k2_proto(
    const float* __restrict__ th, const float* __restrict__ fclw, const float* __restrict__ fclb,
    const float* __restrict__ projw, const float* __restrict__ convw, const float* __restrict__ convb,
    float* __restrict__ pv, float* __restrict__ pvsq, float* __restrict__ ctab,
    ushort_t* __restrict__ wb)
{
  const int p = blockIdx.x, h = threadIdx.x;
  __shared__ float thr[2*NHID], t1[NHID], pvr[NHID];
  thr[h]      = th[p*2*NHID+h];
  thr[NHID+h] = th[p*2*NHID+NHID+h];
  __syncthreads();
  float acc = fclb[h];
  for (int k=0;k<2*NHID;k++) acc += thr[k]*fclw[h*2*NHID+k];
  t1[h] = fmaxf(acc,0.f);
  __syncthreads();
  float pvh = 0.f;
  for (int k=0;k<NHID;k++) pvh += t1[k]*projw[h*NHID+k];
  pv[p*NHID+h]=pvh; pvr[h]=pvh;
  wb[WO_PV + p*64 + h] = f2bf(pvh);
  if (p==0){
    #pragma unroll
    for (int r=24;r<32;r++) wb[WO_PV + r*64 + h] = (ushort_t)0;
  }
  __syncthreads();
  float ct = convb[h];
  for (int k=0;k<NHID;k++) ct += pvr[k]*convw[h*2*NHID+NHID+k];
  ctab[p*NHID+h]=ct;
  if (h==0){ float s=0.f; for (int k=0;k<NHID;k++) s+=pvr[k]*pvr[k]; pvsq[p]=s; }
}

// ---------------- K3: MFMA distances+logits+argmax+conv + BN partials ----------------
// stage/distances/logits/argmax wave-local (fences); ONE barrier before the
// cross-wave conv. Stage loads issued before weight-frag loads.
__global__ __launch_bounds__(256) void k3_mfma(
    const float* __restrict__ inp, const int* __restrict__ month,
    const float* __restrict__ pvsq, const float* __restrict__ ctab,
    const float* __restrict__ lastw, const ushort_t* __restrict__ wb,
    float* __restrict__ out_logits, float* __restrict__ out_md,
    ushort_t* __restrict__ xgb, float* __restrict__ part1, float* __restrict__ part2)
{
  __shared__ ushort_t xl[64*72];     // x rows bf16
  __shared__ float insql[64];        // fp32 row ||x||^2
  __shared__ float pal[64*26];       // prototype activations (wave-local use)

  const int t = threadIdx.x;
  const int w = t>>6, lane = t&63;
  const int l15 = lane&15, kg = lane>>4, ko = kg*8;
  const int gcol = w*16 + l15;
  const int rbase = w*16;
  const int rowA = rbase + l15;
  const size_t rowblk = (size_t)blockIdx.x*64;

  // ---- stage loads FIRST (oldest in vmcnt queue) ----
  const int sr = t>>2, scb = (t&3)*16;
  float4 xr[4];
  #pragma unroll
  for (int i=0;i<4;i++)
    xr[i] = *reinterpret_cast<const float4*>(inp + (rowblk + sr)*64 + scb + i*4);
  const int mo = month[blockIdx.x*4 + w];

  // ---- weight fragments (land under stage processing) ----
  const short8 pv0a = LD8(wb + WO_PV + l15*64 + ko);
  const short8 pv0b = LD8(wb + WO_PV + l15*64 + 32 + ko);
  const short8 pv1a = LD8(wb + WO_PV + (16+l15)*64 + ko);
  const short8 pv1b = LD8(wb + WO_PV + (16+l15)*64 + 32 + ko);
  const short8 cw0  = LD8(wb + WO_CVX + gcol*64 + ko);
  const short8 cw1  = LD8(wb + WO_CVX + gcol*64 + 32 + ko);
  const float pq0 = pvsq[l15];
  const float pq1 = (l15<8)? pvsq[16+l15] : 0.f;
  const int season = ((mo+10)%12)/3;

  // ---- stage x -> bf16 LDS + fp32 insq (wave-local rows) ----
  {
    float ss = 0.f;
    #pragma unroll
    for (int i=0;i<4;i++){
      const float4 xv = xr[i];
      ss += xv.x*xv.x + xv.y*xv.y + xv.z*xv.z + xv.w*xv.w;
      uint2 yy; yy.x = pk2bf(xv.x, xv.y); yy.y = pk2bf(xv.z, xv.w);
      *reinterpret_cast<uint2*>(&xl[sr*72 + scb + i*4]) = yy;
    }
    ss += __shfl_xor(ss,1,4);
    ss += __shfl_xor(ss,2,4);
    if ((t&3)==0) insql[sr] = ss;
  }
  LDSFENCE();

  const short8 ax0 = LD8(&xl[rowA*72+ko]);
  const short8 ax1 = LD8(&xl[rowA*72+32+ko]);

  // ---- distances: xp = X . PV^T (wave-row decomp) ----
  f32x4 d0={0.f,0.f,0.f,0.f}, d1=d0;
  d0 = MFMA(ax0, pv0a, d0);
  d0 = MFMA(ax1, pv0b, d0);
  d1 = MFMA(ax0, pv1a, d1);
  d1 = MFMA(ax1, pv1b, d1);
  {
    #pragma unroll
    for (int j=0;j<4;j++){
      const int rloc = rbase + kg*4 + j;
      const float iq = insql[rloc];
      const float md0 = iq + pq0 - 2.f*d0[j];
      out_md[(rowblk+rloc)*24 + l15] = md0;
      pal[rloc*26 + l15] = __logf(md0+1.f) - __logf(md0+EPS_P);
      const float md1 = iq + pq1 - 2.f*d1[j];
      const float pa1 = __logf(md1+1.f) - __logf(md1+EPS_P);
      if (l15<8){
        out_md[(rowblk+rloc)*24 + 16+l15] = md1;
        pal[rloc*26 + 16+l15] = pa1;
      }
    }
  }
  LDSFENCE();   // own pal rows committed

  // ---- logits (wave-local rows) ----
  {
    const int r2 = rbase + (lane>>2), c = lane&3;
    float lgv = 0.f;
    #pragma unroll
    for (int p=0;p<24;p++) lgv += pal[r2*26+p]*lastw[c*24+p];
    out_logits[(rowblk+r2)*4 + c] = lgv;
  }

  // ---- month argmax over 6 seasonal protos (in-register result) ----
  int qsw;
  {
    float simv = -3.4e38f;
    const int j6 = lane & 7;
    if (j6 < 6){
      simv = 0.f;
      const int sp = season*6 + j6;
      #pragma unroll
      for (int i=0;i<16;i++) simv += pal[(rbase+i)*26 + sp];
    }
    int bidx = j6;
    { const float ov=__shfl_xor(simv,1,8); const int oi=__shfl_xor(bidx,1,8);
      if (ov>simv || (ov==simv && oi<bidx)){ simv=ov; bidx=oi; } }
    { const float ov=__shfl_xor(simv,2,8); const int oi=__shfl_xor(bidx,2,8);
      if (ov>simv || (ov==simv && oi<bidx)){ simv=ov; bidx=oi; } }
    { const float ov=__shfl_xor(simv,4,8); const int oi=__shfl_xor(bidx,4,8);
      if (ov>simv || (ov==simv && oi<bidx)){ simv=ov; bidx=oi; } }
    qsw = season*6 + bidx;
  }
  __syncthreads();   // all waves' xl visible for cross-wave conv

  // ---- conv: col-tile per wave, weights loop-invariant; bf16 block-local out ----
  ushort_t* xgblk = xgb + (size_t)blockIdx.x*8192;
  const float cg = ctab[qsw*64 + gcol];
  float s1=0.f, s2=0.f;
  #pragma unroll
  for (int rg=0; rg<4; rg++){
    const int ra = rg*16 + l15;
    const short8 bx0 = LD8(&xl[ra*72+ko]);
    const short8 bx1 = LD8(&xl[ra*72+32+ko]);
    f32x4 ac={0.f,0.f,0.f,0.f};
    ac = MFMA(bx0, cw0, ac);
    ac = MFMA(bx1, cw1, ac);
    #pragma unroll
    for (int j=0;j<4;j++){
      const int rloc = rg*16 + kg*4 + j;
      const float v = ac[j] + cg;
      xgblk[rloc*64 + gcol] = f2bf_hw(v);
      s1 += v; s2 += v*v;
    }
  }
  s1 += __shfl_xor(s1,16); s1 += __shfl_xor(s1,32);
  s2 += __shfl_xor(s2,16); s2 += __shfl_xor(s2,32);
  if (kg==0){
    part1[(size_t)blockIdx.x*64 + gcol] = s1;
    part2[(size_t)blockIdx.x*64 + gcol] = s2;
  }
}

// ---------------- K4b: partials [4096][64] -> mid [64][64] f64 ----------------
__global__ __launch_bounds__(64) void k4b_reduce(
    const float* __restrict__ part1, const float* __restrict__ part2,
    double* __restrict__ mid1, double* __restrict__ mid2)
{
  const int i = blockIdx.x, c = threadIdx.x;
  double s1=0.0, s2=0.0;
  for (int b=i*64; b<i*64+64; b++){
    s1 += (double)part1[b*64+c];
    s2 += (double)part2[b*64+c];
  }
  mid1[i*64+c]=s1; mid2[i*64+c]=s2;
}

// ---------------- K5: BN stats finalize ----------------
__global__ __launch_bounds__(64) void k5_finalize(
    const double* __restrict__ mid1, const double* __restrict__ mid2,
    const float* __restrict__ bng, const float* __restrict__ bnb,
    float* __restrict__ bnsc, float* __restrict__ bnsh)
{
  const int f = threadIdx.x;
  double s1=0.0, s2=0.0;
  for (int i=0;i<64;i++){ s1+=mid1[i*64+f]; s2+=mid2[i*64+f]; }
  const double mu = s1 / (double)NROWS;
  double var = s2/(double)NROWS - mu*mu;
  if (var < 0.0) var = 0.0;
  const float sc = bng[f] * (float)(1.0/sqrt(var + (double)EPS_BN));
  bnsc[f]=sc;
  bnsh[f]=bnb[f]-(float)mu*sc;
}

// ---------------- K6: MFMA  BN->fc1->LN->GRU->head ----------------
// stage/fc1/LN wave-local (fence); 3 barriers: pre-GRU, pre-h-scatter, pre-head.
// Stage loads issued before weight-frag loads. GRU weights register-invariant.
__global__ __launch_bounds__(256) void k6_mfma(
    const ushort_t* __restrict__ xgb, const float* __restrict__ hidden,
    const float* __restrict__ bnsc, const float* __restrict__ bnsh,
    const float* __restrict__ fc1b, const float* __restrict__ lng, const float* __restrict__ lnb,
    const float* __restrict__ gbih, const float* __restrict__ gbhh,
    const float* __restrict__ outb,
    const ushort_t* __restrict__ wb,
    float* __restrict__ out_a, float* __restrict__ out_h)
{
  __shared__ ushort_t ybuf[64*LPAD];   // y -> ttl -> hvl (phased reuse)
  __shared__ ushort_t hidl[64*LPAD];
  const int t = threadIdx.x;
  const int lane = t & 63, w = t >> 6;
  const int l15 = lane & 15, kg = lane >> 4;
  const int ko = kg*8;
  const int rbase = w*16;
  const int rowA = rbase + l15;
  const int sr = t>>2, scb = (t&3)*16;

  // ---- stage loads FIRST (oldest in vmcnt queue) ----
  const ushort_t* xgp = xgb + (size_t)blockIdx.x*8192 + sr*64 + scb;
  const us8 xv0 = *reinterpret_cast<const us8*>(xgp);
  const us8 xv1 = *reinterpret_cast<const us8*>(xgp+8);
  const size_t g = ((size_t)blockIdx.x*64 + sr)*64 + scb;
  float4 hv4[4];
  #pragma unroll
  for (int i=0;i<4;i++)
    hv4[i] = *reinterpret_cast<const float4*>(hidden + g + i*4);

  // ---- fc1 weight frags (land under stage processing) ----
  const short8 f0a = LD8(wb + WO_FC1 + ( 0+l15)*64 + ko);
  const short8 f0b = LD8(wb + WO_FC1 + ( 0+l15)*64 + 32 + ko);
  const short8 f1a = LD8(wb + WO_FC1 + (16+l15)*64 + ko);
  const short8 f1b = LD8(wb + WO_FC1 + (16+l15)*64 + 32 + ko);
  const short8 f2a = LD8(wb + WO_FC1 + (32+l15)*64 + ko);
  const short8 f2b = LD8(wb + WO_FC1 + (32+l15)*64 + 32 + ko);
  const short8 f3a = LD8(wb + WO_FC1 + (48+l15)*64 + ko);
  const short8 f3b = LD8(wb + WO_FC1 + (48+l15)*64 + 32 + ko);

  // ---- stage: BN+relu(x_bf16) and hidden -> bf16 LDS (wave-local rows) ----
  {
    float xf[16];
    #pragma unroll
    for (int e=0;e<8;e++){ xf[e]=bf2f(xv0[e]); xf[8+e]=bf2f(xv1[e]); }
    #pragma unroll
    for (int i=0;i<4;i++){
      const float4 sc = *reinterpret_cast<const float4*>(bnsc + scb + i*4);
      const float4 sh = *reinterpret_cast<const float4*>(bnsh + scb + i*4);
      const float y0 = fmaxf(xf[4*i  ]*sc.x+sh.x, 0.f);
      const float y1 = fmaxf(xf[4*i+1]*sc.y+sh.y, 0.f);
      const float y2 = fmaxf(xf[4*i+2]*sc.z+sh.z, 0.f);
      const float y3 = fmaxf(xf[4*i+3]*sc.w+sh.w, 0.f);
      uint2 yy; yy.x = pk2bf(y0,y1); yy.y = pk2bf(y2,y3);
      *reinterpret_cast<uint2*>(&ybuf[sr*LPAD + scb + i*4]) = yy;
      const float4 h4 = hv4[i];
      uint2 hh; hh.x = pk2bf(h4.x,h4.y); hh.y = pk2bf(h4.z,h4.w);
      *reinterpret_cast<uint2*>(&hidl[sr*LPAD + scb + i*4]) = hh;
    }
  }
  LDSFENCE();   // own stage rows committed (fc1 reads own rows only)

  const short8 ay0 = LD8(&ybuf[rowA*LPAD + ko]);
  const short8 ay1 = LD8(&ybuf[rowA*LPAD + 32 + ko]);

  // ---- fc1 (wave-row decomp, preloaded frags) ----
  f32x4 ac0={0.f,0.f,0.f,0.f}, ac1=ac0, ac2=ac0, ac3=ac0;
  ac0 = MFMA(ay0, f0a, ac0);  ac0 = MFMA(ay1, f0b, ac0);
  ac1 = MFMA(ay0, f1a, ac1);  ac1 = MFMA(ay1, f1b, ac1);
  ac2 = MFMA(ay0, f2a, ac2);  ac2 = MFMA(ay1, f2b, ac2);
  ac3 = MFMA(ay0, f3a, ac3);  ac3 = MFMA(ay1, f3b, ac3);
  {
    const float b0=fc1b[l15], b1=fc1b[16+l15], b2=fc1b[32+l15], b3=fc1b[48+l15];
    float tn0[4], tn1[4], tn2[4], tn3[4], mu[4], rs[4];
    #pragma unroll
    for (int j=0;j<4;j++){ tn0[j]=ac0[j]+b0; tn1[j]=ac1[j]+b1; tn2[j]=ac2[j]+b2; tn3[j]=ac3[j]+b3; }
    #pragma unroll
    for (int j=0;j<4;j++){
      float s = tn0[j]+tn1[j]+tn2[j]+tn3[j];
      s += __shfl_xor(s,1,16); s += __shfl_xor(s,2,16);
      s += __shfl_xor(s,4,16); s += __shfl_xor(s,8,16);
      mu[j] = s*(1.f/64.f);
    }
    #pragma unroll
    for (int j=0;j<4;j++){
      const float d0_=tn0[j]-mu[j], d1_=tn1[j]-mu[j], d2_=tn2[j]-mu[j], d3_=tn3[j]-mu[j];
      float v = d0_*d0_+d1_*d1_+d2_*d2_+d3_*d3_;
      v += __shfl_xor(v,1,16); v += __shfl_xor(v,2,16);
      v += __shfl_xor(v,4,16); v += __shfl_xor(v,8,16);
      rs[j] = 1.f/sqrtf(v*(1.f/64.f)+EPS_LN);
    }
    const float g0=lng[l15], g1=lng[16+l15], g2=lng[32+l15], g3=lng[48+l15];
    const float q0=lnb[l15], q1=lnb[16+l15], q2=lnb[32+l15], q3=lnb[48+l15];
    // LN into own stripe; antidep vs own ay reads is program order.
    #pragma unroll
    for (int j=0;j<4;j++){
      const int rr_ = rbase + kg*4 + j;
      ybuf[rr_*LPAD +      l15] = f2bf_hw(fmaxf((tn0[j]-mu[j])*rs[j]*g0+q0, 0.f));
      ybuf[rr_*LPAD + 16 + l15] = f2bf_hw(fmaxf((tn1[j]-mu[j])*rs[j]*g1+q1, 0.f));
      ybuf[rr_*LPAD + 32 + l15] = f2bf_hw(fmaxf((tn2[j]-mu[j])*rs[j]*g2+q2, 0.f));
      ybuf[rr_*LPAD + 48 + l15] = f2bf_hw(fmaxf((tn3[j]-mu[j])*rs[j]*g3+q3, 0.f));
    }
  }

  // ---- prefetch GRU (col gcol) weight frags + biases; land during barrier ----
  const int gcol = w*16 + l15;
  const ushort_t* gih = wb + WO_GIH;
  const ushort_t* ghh = wb + WO_GHH;
  const short8 wr0 = LD8(gih + (      gcol)*64 + ko);
  const short8 wr1 = LD8(gih + (      gcol)*64 + 32 + ko);
  const short8 wz0 = LD8(gih + ( 64 + gcol)*64 + ko);
  const short8 wz1 = LD8(gih + ( 64 + gcol)*64 + 32 + ko);
  const short8 wn0 = LD8(gih + (128 + gcol)*64 + ko);
  const short8 wn1 = LD8(gih + (128 + gcol)*64 + 32 + ko);
  const short8 vr0 = LD8(ghh + (      gcol)*64 + ko);
  const short8 vr1 = LD8(ghh + (      gcol)*64 + 32 + ko);
  const short8 vz0 = LD8(ghh + ( 64 + gcol)*64 + ko);
  const short8 vz1 = LD8(ghh + ( 64 + gcol)*64 + 32 + ko);
  const short8 vn0 = LD8(ghh + (128 + gcol)*64 + ko);
  const short8 vn1 = LD8(ghh + (128 + gcol)*64 + 32 + ko);
  const float bir=gbih[gcol],     bhr=gbhh[gcol];
  const float biz=gbih[64+gcol],  bhz=gbhh[64+gcol];
  const float bin_=gbih[128+gcol],bhn=gbhh[128+gcol];
  __syncthreads();   // ttl + all waves' stage visible

  // ---- GRU: col-tile per wave, 4 row-groups; keep h bf16 in regs ----
  us4 hkeep[4];
  #pragma unroll
  for (int rg=0; rg<4; rg++){
    const int ra = rg*16 + l15;
    const short8 at0 = LD8(&ybuf[ra*LPAD + ko]);
    const short8 at1 = LD8(&ybuf[ra*LPAD + 32 + ko]);
    const short8 bh0 = LD8(&hidl[ra*LPAD + ko]);
    const short8 bh1 = LD8(&hidl[ra*LPAD + 32 + ko]);
    f32x4 ar={0.f,0.f,0.f,0.f}, az=ar, an=ar, hn=ar;
    ar = MFMA(at0, wr0, ar);  ar = MFMA(at1, wr1, ar);
    ar = MFMA(bh0, vr0, ar);  ar = MFMA(bh1, vr1, ar);
    az = MFMA(at0, wz0, az);  az = MFMA(at1, wz1, az);
    az = MFMA(bh0, vz0, az);  az = MFMA(bh1, vz1, az);
    an = MFMA(at0, wn0, an);  an = MFMA(at1, wn1, an);
    hn = MFMA(bh0, vn0, hn);  hn = MFMA(bh1, vn1, hn);
    us4 hb4;
    #pragma unroll
    for (int j=0;j<4;j++){
      const int rloc = rg*16 + kg*4 + j;
      const size_t rg_ = (size_t)blockIdx.x*64 + rloc;
      const float rrg = fsig(ar[j]+bir+bhr);
      const float zzg = fsig(az[j]+biz+bhz);
      const float nng = ftanh(an[j]+bin_ + rrg*(hn[j]+bhn));
      const float hold = bf2f(hidl[rloc*LPAD + gcol]);
      const float hv = (1.f-zzg)*nng + zzg*hold;
      out_h[rg_*64 + gcol] = hv;
      hb4[j] = f2bf_hw(hv);
    }
    hkeep[rg] = hb4;
  }

  // ---- head weight frags + bias: issue now, latency hides under the barriers ----
  const short8 ow0 = LD8(wb + WO_OUT + l15*64 + ko);
  const short8 ow1 = LD8(wb + WO_OUT + l15*64 + 32 + ko);
  const float ob = (l15 < 12) ? outb[l15] : 0.f;

  __syncthreads();   // all waves done reading ttl/hidl -> ybuf reusable as hvl
  #pragma unroll
  for (int rg=0; rg<4; rg++){
    #pragma unroll
    for (int j=0;j<4;j++)
      ybuf[(rg*16 + kg*4 + j)*LPAD + gcol] = hkeep[rg][j];
  }
  __syncthreads();   // hvl ready

  // ---- output head (wave-row decomp) ----
  const short8 av0 = LD8(&ybuf[rowA*LPAD + ko]);
  const short8 av1 = LD8(&ybuf[rowA*LPAD + 32 + ko]);
  f32x4 aa={0.f,0.f,0.f,0.f};
  aa = MFMA(av0, ow0, aa);
  aa = MFMA(av1, ow1, aa);
  if (l15 < 12){
    #pragma unroll
    for (int j=0;j<4;j++){
      const size_t rg_ = (size_t)blockIdx.x*64 + rbase + kg*4 + j;
      out_a[rg_*12 + l15] = aa[j] + ob;
    }
  }
}

extern "C" void kernel_launch(void* const* d_in, const int* in_sizes, int n_in,
                              void* d_out, int out_size, void* d_ws, size_t ws_size,
                              hipStream_t stream)
{
  (void)in_sizes; (void)n_in; (void)out_size; (void)ws_size;
  const float* inputs = (const float*)d_in[0];
  const float* hidden = (const float*)d_in[1];
  const int*   month  = (const int*)d_in[2];
  const float* jq     = (const float*)d_in[3];
  const float* wif    = (const float*)d_in[4];
  const float* whf    = (const float*)d_in[5];
  const float* bif    = (const float*)d_in[6];
  const float* bhf    = (const float*)d_in[7];
  const float* wib    = (const float*)d_in[8];
  const float* bib    = (const float*)d_in[10];
  const float* bhb    = (const float*)d_in[11];
  const float* fclw   = (const float*)d_in[12];
  const float* fclb   = (const float*)d_in[13];
  const float* projw  = (const float*)d_in[14];
  const float* convw  = (const float*)d_in[15];
  const float* convb  = (const float*)d_in[16];
  const float* bng    = (const float*)d_in[17];
  const float* bnb    = (const float*)d_in[18];
  const float* fc1w   = (const float*)d_in[19];
  const float* fc1b   = (const float*)d_in[20];
  const float* lng    = (const float*)d_in[21];
  const float* lnb    = (const float*)d_in[22];
  const float* gwih   = (const float*)d_in[23];
  const float* gwhh   = (const float*)d_in[24];
  const float* gbih   = (const float*)d_in[25];
  const float* gbhh   = (const float*)d_in[26];
  const float* outw   = (const float*)d_in[27];
  const float* outb   = (const float*)d_in[28];
  const float* lastw  = (const float*)d_in[29];

  float* ws  = (float*)d_ws;
  float* out = (float*)d_out;
  float* out_a  = out;
  float* out_h  = out + (size_t)NROWS*NACT;
  float* out_lg = out + (size_t)NROWS*(NACT+NHID);
  float* out_md = out + (size_t)NROWS*(NACT+NHID+4);
  ushort_t* wb = (ushort_t*)(ws + WS_WBF16);
  ushort_t* xgb = (ushort_t*)out_h;     // bf16 x_glb, block-local packed
  float* part1 = out_a;                 // [4096][64]
  float* part2 = out_a + (size_t)4096*64;

  hipLaunchKernelGGL(k1_lstm, dim3(NPROTO+4), dim3(256), 0, stream,
                     jq, wif, whf, bif, bhf, wib, bib, bhb,
                     fc1w, gwih, gwhh, outw, convw, wb, ws+WS_TH);
  hipLaunchKernelGGL(k2_proto, dim3(NPROTO), dim3(64), 0, stream,
                     ws+WS_TH, fclw, fclb, projw, convw, convb,
                     ws+WS_PV, ws+WS_PVSQ, ws+WS_CTAB, wb);
  hipLaunchKernelGGL(k3_mfma, dim3(NROWS/64), dim3(256), 0, stream,
                     inputs, month, ws+WS_PVSQ, ws+WS_CTAB, lastw, wb,
                     out_lg, out_md, xgb, part1, part2);
  hipLaunchKernelGGL(k4b_reduce, dim3(64), dim3(64), 0, stream,
                     part1, part2, (double*)(ws+WS_MID1), (double*)(ws+WS_MID2));
  hipLaunchKernelGGL(k5_finalize, dim3(1), dim3(64), 0, stream,
                     (const double*)(ws+WS_MID1), (const double*)(ws+WS_MID2),
                     bng, bnb, ws+WS_BNSC, ws+WS_BNSH);
  hipLaunchKernelGGL(k6_mfma, dim3(NROWS/64), dim3(256), 0, stream,
                     xgb, hidden, ws+WS_BNSC, ws+WS_BNSH, fc1b, lng, lnb,
                     gbih, gbhh, outb, wb, out_a, out_h);
}

// Round 5
// 144.200 us; speedup vs baseline: 1.6943x; 1.0078x over previous
//
#include <hip/hip_runtime.h>
#include <cmath>

#define NHID 64
#define NMONTH 16384
#define NAGENT 16
#define NROWS (NMONTH*NAGENT)   // 262144
#define NPROTO 24
#define TSEQ 32
#define NACT 12
#define EPS_P  1e-4f
#define EPS_BN 1e-5f
#define EPS_LN 1e-5f

typedef __attribute__((ext_vector_type(8))) short short8;
typedef __attribute__((ext_vector_type(4))) float f32x4;
typedef __attribute__((ext_vector_type(4))) unsigned short us4;
typedef __attribute__((ext_vector_type(8))) unsigned short us8;
typedef unsigned short ushort_t;

#define MFMA(a,b,c) __builtin_amdgcn_mfma_f32_16x16x32_bf16(a,b,c,0,0,0)
#define LPAD 68   // k6 LDS row stride (ushorts): 136B = 34 dwords -> 2-way (free)
#define LDSFENCE() asm volatile("s_waitcnt lgkmcnt(0)" ::: "memory")
#define LD8(P) (*reinterpret_cast<const short8*>(P))

typedef const __attribute__((address_space(1))) void* gvp;
typedef __attribute__((address_space(3))) void* lvp;

// ---- ws layout (float offsets) ----
#define WS_TH     0        // [24][128] f32
#define WS_PV     3072     // [24][64]  f32
#define WS_PVSQ   4608     // [24] (pad 32)
#define WS_CTAB   4640     // [24][64]
#define WS_MID1   6176     // [64][64] f64 -> 8192 floats
#define WS_MID2   14368    // [64][64] f64
#define WS_BNSC   22560    // [64]
#define WS_BNSH   22624    // [64]
#define WS_WBF16  22688    // ushort region below
#define WO_FC1   0         // fc1w bf16 [64][64]
#define WO_GIH   4096      // gwih bf16 [192][64]
#define WO_GHH   16384     // gwhh bf16 [192][64]
#define WO_OUT   28672     // outw bf16 [16][64] (rows 12-15 zero)
#define WO_PV    29696     // pv bf16 [32][64] (rows 24-31 zero)
#define WO_CVX   31744     // convw[:, :64] bf16 [64][64]

__device__ __forceinline__ float sigf(float x){ return 1.0f/(1.0f+expf(-x)); }
__device__ __forceinline__ float fsig(float x){
  return __builtin_amdgcn_rcpf(1.f + __expf(-x));
}
__device__ __forceinline__ float ftanh(float x){
  return 1.f - 2.f*__builtin_amdgcn_rcpf(1.f + __expf(2.f*x));
}
__device__ __forceinline__ ushort_t f2bf(float f){
  unsigned u = __builtin_bit_cast(unsigned, f);
  u += 0x7FFFu + ((u>>16)&1u);           // round-to-nearest-even
  return (ushort_t)(u>>16);
}
__device__ __forceinline__ float bf2f(ushort_t b){
  return __builtin_bit_cast(float, ((unsigned)b)<<16);
}
// HW packed f32x2 -> bf16x2 (RNE), 1 VALU instr
__device__ __forceinline__ unsigned pk2bf(float a, float b){
  unsigned d;
  asm("v_cvt_pk_bf16_f32 %0, %1, %2" : "=v"(d) : "v"(a), "v"(b));
  return d;
}
// 1-instr scalar f32->bf16 (low half of cvt_pk)
__device__ __forceinline__ ushort_t f2bf_hw(float x){
  unsigned d;
  asm("v_cvt_pk_bf16_f32 %0, %1, %2" : "=v"(d) : "v"(x), "v"(x));
  return (ushort_t)d;
}
// build bf16 A-frag (8 elems = logical f32 cols base*4 .. base*4+7) for row ra
// from chunk-swizzled f32 LDS slab hraw[64][64] (phys chunk = logical ^ (ra&15))
__device__ __forceinline__ short8 hfrag(const float* hraw, int ra, int base){
  const int r15 = ra & 15;
  const float4 a = *reinterpret_cast<const float4*>(&hraw[ra*64 + (((base  )^r15)<<2)]);
  const float4 b = *reinterpret_cast<const float4*>(&hraw[ra*64 + (((base+1)^r15)<<2)]);
  uint4 u; u.x=pk2bf(a.x,a.y); u.y=pk2bf(a.z,a.w); u.z=pk2bf(b.x,b.y); u.w=pk2bf(b.z,b.w);
  return __builtin_bit_cast(short8, u);
}

// ---------------- K1: biLSTM (blocks 0-23) + static weight->bf16 conv (blocks 24-27) ----------------
__global__ __launch_bounds__(256) void k1_lstm(
    const float* __restrict__ jq,
    const float* __restrict__ wif, const float* __restrict__ whf,
    const float* __restrict__ bif, const float* __restrict__ bhf,
    const float* __restrict__ wib, const float* __restrict__ bib, const float* __restrict__ bhb,
    const float* __restrict__ fc1w, const float* __restrict__ gwih,
    const float* __restrict__ gwhh, const float* __restrict__ outw,
    const float* __restrict__ convw, ushort_t* __restrict__ wb,
    float* __restrict__ th)
{
  __shared__ float hs[NHID];
  __shared__ float gs[4*NHID];
  if (blockIdx.x >= NPROTO){
    const int tt = (blockIdx.x - NPROTO)*256 + threadIdx.x;   // 0..1023
    for (int i=tt;i<4096;i+=1024)  wb[WO_FC1+i]=f2bf(fc1w[i]);
    for (int i=tt;i<12288;i+=1024){ wb[WO_GIH+i]=f2bf(gwih[i]); wb[WO_GHH+i]=f2bf(gwhh[i]); }
    for (int i=tt;i<1024;i+=1024)  wb[WO_OUT+i] = (i<768)? f2bf(outw[i]) : (ushort_t)0;
    for (int i=tt;i<4096;i+=1024)  wb[WO_CVX+i] = f2bf(convw[(i>>6)*128 + (i&63)]);
    return;
  }
  const int p = blockIdx.x;
  const int j = threadIdx.x;
  float wh[NHID];
  #pragma unroll
  for (int k=0;k<NHID;k++) wh[k] = whf[j*NHID+k];
  const float wi0=wif[j*3], wi1=wif[j*3+1], wi2=wif[j*3+2];
  const float bj = bif[j]+bhf[j];
  float c = 0.f;
  if (j < NHID) hs[j] = 0.f;
  __syncthreads();
  for (int t=0;t<TSEQ;t++){
    const float x0=jq[(p*TSEQ+t)*3], x1=jq[(p*TSEQ+t)*3+1], x2=jq[(p*TSEQ+t)*3+2];
    float g = wi0*x0+wi1*x1+wi2*x2+bj;
    #pragma unroll
    for (int k=0;k<NHID;k++) g += wh[k]*hs[k];
    __syncthreads();
    gs[j] = g;
    __syncthreads();
    if (j < NHID){
      const float gi=gs[j], gf=gs[NHID+j], gg=gs[2*NHID+j], go=gs[3*NHID+j];
      c = sigf(gf)*c + sigf(gi)*tanhf(gg);
      hs[j] = sigf(go)*tanhf(c);
    }
    __syncthreads();
  }
  if (j < NHID) th[p*2*NHID + j] = hs[j];
  const float x0=jq[(p*TSEQ+TSEQ-1)*3], x1=jq[(p*TSEQ+TSEQ-1)*3+1], x2=jq[(p*TSEQ+TSEQ-1)*3+2];
  const float gb = wib[j*3]*x0 + wib[j*3+1]*x1 + wib[j*3+2]*x2 + bib[j]+bhb[j];
  __syncthreads();
  gs[j] = gb;
  __syncthreads();
  if (j < NHID){
    const float gi=gs[j], gg=gs[2*NHID+j], go=gs[3*NHID+j];
    const float cb = sigf(gi)*tanhf(gg);
    th[p*2*NHID + NHID + j] = sigf(go)*tanhf(cb);
  }
}

// ---------------- K2: prototype vectors, pv^2, conv "chosen" table, pv->bf16 ----------------
__global__ __launch_bounds__(64) void k2_proto(
    const float* __restrict__ th, const float* __restrict__ fclw, const float* __restrict__ fclb,
    const float* __restrict__ projw, const float* __restrict__ convw, const float* __restrict__ convb,
    float* __restrict__ pv, float* __restrict__ pvsq, float* __restrict__ ctab,
    ushort_t* __restrict__ wb)
{
  const int p = blockIdx.x, h = threadIdx.x;
  __shared__ float thr[2*NHID], t1[NHID], pvr[NHID];
  thr[h]      = th[p*2*NHID+h];
  thr[NHID+h] = th[p*2*NHID+NHID+h];
  __syncthreads();
  float acc = fclb[h];
  for (int k=0;k<2*NHID;k++) acc += thr[k]*fclw[h*2*NHID+k];
  t1[h] = fmaxf(acc,0.f);
  __syncthreads();
  float pvh = 0.f;
  for (int k=0;k<NHID;k++) pvh += t1[k]*projw[h*NHID+k];
  pv[p*NHID+h]=pvh; pvr[h]=pvh;
  wb[WO_PV + p*64 + h] = f2bf(pvh);
  if (p==0){
    #pragma unroll
    for (int r=24;r<32;r++) wb[WO_PV + r*64 + h] = (ushort_t)0;
  }
  __syncthreads();
  float ct = convb[h];
  for (int k=0;k<NHID;k++) ct += pvr[k]*convw[h*2*NHID+NHID+k];
  ctab[p*NHID+h]=ct;
  if (h==0){ float s=0.f; for (int k=0;k<NHID;k++) s+=pvr[k]*pvr[k]; pvsq[p]=s; }
}

// ---------------- K3: MFMA distances+logits+argmax+conv + BN partials ----------------
// stage/distances/logits/argmax wave-local (fences); ONE barrier before the
// cross-wave conv. Stage loads issued before weight-frag loads.
__global__ __launch_bounds__(256) void k3_mfma(
    const float* __restrict__ inp, const int* __restrict__ month,
    const float* __restrict__ pvsq, const float* __restrict__ ctab,
    const float* __restrict__ lastw, const ushort_t* __restrict__ wb,
    float* __restrict__ out_logits, float* __restrict__ out_md,
    ushort_t* __restrict__ xgb, float* __restrict__ part1, float* __restrict__ part2)
{
  __shared__ ushort_t xl[64*72];     // x rows bf16
  __shared__ float insql[64];        // fp32 row ||x||^2
  __shared__ float pal[64*26];       // prototype activations (wave-local use)

  const int t = threadIdx.x;
  const int w = t>>6, lane = t&63;
  const int l15 = lane&15, kg = lane>>4, ko = kg*8;
  const int gcol = w*16 + l15;
  const int rbase = w*16;
  const int rowA = rbase + l15;
  const size_t rowblk = (size_t)blockIdx.x*64;

  // ---- stage loads FIRST (oldest in vmcnt queue) ----
  const int sr = t>>2, scb = (t&3)*16;
  float4 xr[4];
  #pragma unroll
  for (int i=0;i<4;i++)
    xr[i] = *reinterpret_cast<const float4*>(inp + (rowblk + sr)*64 + scb + i*4);
  const int mo = month[blockIdx.x*4 + w];

  // ---- weight fragments (land under stage processing) ----
  const short8 pv0a = LD8(wb + WO_PV + l15*64 + ko);
  const short8 pv0b = LD8(wb + WO_PV + l15*64 + 32 + ko);
  const short8 pv1a = LD8(wb + WO_PV + (16+l15)*64 + ko);
  const short8 pv1b = LD8(wb + WO_PV + (16+l15)*64 + 32 + ko);
  const short8 cw0  = LD8(wb + WO_CVX + gcol*64 + ko);
  const short8 cw1  = LD8(wb + WO_CVX + gcol*64 + 32 + ko);
  const float pq0 = pvsq[l15];
  const float pq1 = (l15<8)? pvsq[16+l15] : 0.f;
  const int season = ((mo+10)%12)/3;

  // ---- stage x -> bf16 LDS + fp32 insq (wave-local rows) ----
  {
    float ss = 0.f;
    #pragma unroll
    for (int i=0;i<4;i++){
      const float4 xv = xr[i];
      ss += xv.x*xv.x + xv.y*xv.y + xv.z*xv.z + xv.w*xv.w;
      uint2 yy; yy.x = pk2bf(xv.x, xv.y); yy.y = pk2bf(xv.z, xv.w);
      *reinterpret_cast<uint2*>(&xl[sr*72 + scb + i*4]) = yy;
    }
    ss += __shfl_xor(ss,1,4);
    ss += __shfl_xor(ss,2,4);
    if ((t&3)==0) insql[sr] = ss;
  }
  LDSFENCE();

  const short8 ax0 = LD8(&xl[rowA*72+ko]);
  const short8 ax1 = LD8(&xl[rowA*72+32+ko]);

  // ---- distances: xp = X . PV^T (wave-row decomp) ----
  f32x4 d0={0.f,0.f,0.f,0.f}, d1=d0;
  d0 = MFMA(ax0, pv0a, d0);
  d0 = MFMA(ax1, pv0b, d0);
  d1 = MFMA(ax0, pv1a, d1);
  d1 = MFMA(ax1, pv1b, d1);
  {
    #pragma unroll
    for (int j=0;j<4;j++){
      const int rloc = rbase + kg*4 + j;
      const float iq = insql[rloc];
      const float md0 = iq + pq0 - 2.f*d0[j];
      out_md[(rowblk+rloc)*24 + l15] = md0;
      pal[rloc*26 + l15] = __logf(md0+1.f) - __logf(md0+EPS_P);
      const float md1 = iq + pq1 - 2.f*d1[j];
      const float pa1 = __logf(md1+1.f) - __logf(md1+EPS_P);
      if (l15<8){
        out_md[(rowblk+rloc)*24 + 16+l15] = md1;
        pal[rloc*26 + 16+l15] = pa1;
      }
    }
  }
  LDSFENCE();   // own pal rows committed

  // ---- logits (wave-local rows) ----
  {
    const int r2 = rbase + (lane>>2), c = lane&3;
    float lgv = 0.f;
    #pragma unroll
    for (int p=0;p<24;p++) lgv += pal[r2*26+p]*lastw[c*24+p];
    out_logits[(rowblk+r2)*4 + c] = lgv;
  }

  // ---- month argmax over 6 seasonal protos (in-register result) ----
  int qsw;
  {
    float simv = -3.4e38f;
    const int j6 = lane & 7;
    if (j6 < 6){
      simv = 0.f;
      const int sp = season*6 + j6;
      #pragma unroll
      for (int i=0;i<16;i++) simv += pal[(rbase+i)*26 + sp];
    }
    int bidx = j6;
    { const float ov=__shfl_xor(simv,1,8); const int oi=__shfl_xor(bidx,1,8);
      if (ov>simv || (ov==simv && oi<bidx)){ simv=ov; bidx=oi; } }
    { const float ov=__shfl_xor(simv,2,8); const int oi=__shfl_xor(bidx,2,8);
      if (ov>simv || (ov==simv && oi<bidx)){ simv=ov; bidx=oi; } }
    { const float ov=__shfl_xor(simv,4,8); const int oi=__shfl_xor(bidx,4,8);
      if (ov>simv || (ov==simv && oi<bidx)){ simv=ov; bidx=oi; } }
    qsw = season*6 + bidx;
  }
  __syncthreads();   // all waves' xl visible for cross-wave conv

  // ---- conv: col-tile per wave, weights loop-invariant; bf16 block-local out ----
  ushort_t* xgblk = xgb + (size_t)blockIdx.x*8192;
  const float cg = ctab[qsw*64 + gcol];
  float s1=0.f, s2=0.f;
  #pragma unroll
  for (int rg=0; rg<4; rg++){
    const int ra = rg*16 + l15;
    const short8 bx0 = LD8(&xl[ra*72+ko]);
    const short8 bx1 = LD8(&xl[ra*72+32+ko]);
    f32x4 ac={0.f,0.f,0.f,0.f};
    ac = MFMA(bx0, cw0, ac);
    ac = MFMA(bx1, cw1, ac);
    #pragma unroll
    for (int j=0;j<4;j++){
      const int rloc = rg*16 + kg*4 + j;
      const float v = ac[j] + cg;
      xgblk[rloc*64 + gcol] = f2bf_hw(v);
      s1 += v; s2 += v*v;
    }
  }
  s1 += __shfl_xor(s1,16); s1 += __shfl_xor(s1,32);
  s2 += __shfl_xor(s2,16); s2 += __shfl_xor(s2,32);
  if (kg==0){
    part1[(size_t)blockIdx.x*64 + gcol] = s1;
    part2[(size_t)blockIdx.x*64 + gcol] = s2;
  }
}

// ---------------- K4b: partials [4096][64] -> mid [64][64] f64 ----------------
__global__ __launch_bounds__(64) void k4b_reduce(
    const float* __restrict__ part1, const float* __restrict__ part2,
    double* __restrict__ mid1, double* __restrict__ mid2)
{
  const int i = blockIdx.x, c = threadIdx.x;
  double s1=0.0, s2=0.0;
  for (int b=i*64; b<i*64+64; b++){
    s1 += (double)part1[b*64+c];
    s2 += (double)part2[b*64+c];
  }
  mid1[i*64+c]=s1; mid2[i*64+c]=s2;
}

// ---------------- K5: BN stats finalize ----------------
__global__ __launch_bounds__(64) void k5_finalize(
    const double* __restrict__ mid1, const double* __restrict__ mid2,
    const float* __restrict__ bng, const float* __restrict__ bnb,
    float* __restrict__ bnsc, float* __restrict__ bnsh)
{
  const int f = threadIdx.x;
  double s1=0.0, s2=0.0;
  for (int i=0;i<64;i++){ s1+=mid1[i*64+f]; s2+=mid2[i*64+f]; }
  const double mu = s1 / (double)NROWS;
  double var = s2/(double)NROWS - mu*mu;
  if (var < 0.0) var = 0.0;
  const float sc = bng[f] * (float)(1.0/sqrt(var + (double)EPS_BN));
  bnsc[f]=sc;
  bnsh[f]=bnb[f]-(float)mu*sc;
}

// ---------------- K6: MFMA  BN->fc1->LN->GRU->head ----------------
// hidden staged via async global_load_lds DMA into a linear f32 LDS slab
// (source-address chunk-swizzled: phys chunk = logical ^ (row&15)); the DMA
// drains at the pre-GRU barrier, so HBM latency hides under stage+fc1+LN.
// GRU builds bf16 A-frags from f32 LDS (cvt_pk); 'hold' is exact f32.
__global__ __launch_bounds__(256) void k6_mfma(
    const ushort_t* __restrict__ xgb, const float* __restrict__ hidden,
    const float* __restrict__ bnsc, const float* __restrict__ bnsh,
    const float* __restrict__ fc1b, const float* __restrict__ lng, const float* __restrict__ lnb,
    const float* __restrict__ gbih, const float* __restrict__ gbhh,
    const float* __restrict__ outb,
    const ushort_t* __restrict__ wb,
    float* __restrict__ out_a, float* __restrict__ out_h)
{
  __shared__ ushort_t ybuf[64*LPAD];   // y -> ttl -> hvl (phased reuse)
  __shared__ float hraw[64*64];        // f32 hidden slab, chunk-swizzled
  const int t = threadIdx.x;
  const int lane = t & 63, w = t >> 6;
  const int l15 = lane & 15, kg = lane >> 4;
  const int ko = kg*8;
  const int rbase = w*16;
  const int rowA = rbase + l15;
  const int sr = t>>2, scb = (t&3)*16;

  // ---- stage loads FIRST (oldest in vmcnt queue) ----
  const ushort_t* xgp = xgb + (size_t)blockIdx.x*8192 + sr*64 + scb;
  const us8 xv0 = *reinterpret_cast<const us8*>(xgp);
  const us8 xv1 = *reinterpret_cast<const us8*>(xgp+8);

  // ---- fc1 weight frags (land under stage processing) ----
  const short8 f0a = LD8(wb + WO_FC1 + ( 0+l15)*64 + ko);
  const short8 f0b = LD8(wb + WO_FC1 + ( 0+l15)*64 + 32 + ko);
  const short8 f1a = LD8(wb + WO_FC1 + (16+l15)*64 + ko);
  const short8 f1b = LD8(wb + WO_FC1 + (16+l15)*64 + 32 + ko);
  const short8 f2a = LD8(wb + WO_FC1 + (32+l15)*64 + ko);
  const short8 f2b = LD8(wb + WO_FC1 + (32+l15)*64 + 32 + ko);
  const short8 f3a = LD8(wb + WO_FC1 + (48+l15)*64 + ko);
  const short8 f3b = LD8(wb + WO_FC1 + (48+l15)*64 + 32 + ko);

  // ---- async DMA: hidden (16 KB f32) -> hraw, 16 x 1KB, source swizzled ----
  // issued AFTER the loads above so their vmcnt waits leave the DMAs in flight;
  // consumed only after the pre-GRU barrier (which drains vmcnt to 0).
  {
    const float* hbase = hidden + (size_t)blockIdx.x*4096;
    #pragma unroll
    for (int k=0;k<4;k++){
      const int c = (w*4+k)*64 + lane;          // 16B-chunk index
      const int row = c>>4, ccp = c&15;
      const float* src = hbase + row*64 + ((ccp ^ (row&15))<<2);
      float* dst = &hraw[(w*4+k)*256];          // wave-uniform base
      __builtin_amdgcn_global_load_lds((gvp)src, (lvp)dst, 16, 0, 0);
    }
  }

  // ---- stage: BN+relu(x_bf16) -> bf16 LDS (wave-local rows) ----
  {
    float xf[16];
    #pragma unroll
    for (int e=0;e<8;e++){ xf[e]=bf2f(xv0[e]); xf[8+e]=bf2f(xv1[e]); }
    #pragma unroll
    for (int i=0;i<4;i++){
      const float4 sc = *reinterpret_cast<const float4*>(bnsc + scb + i*4);
      const float4 sh = *reinterpret_cast<const float4*>(bnsh + scb + i*4);
      const float y0 = fmaxf(xf[4*i  ]*sc.x+sh.x, 0.f);
      const float y1 = fmaxf(xf[4*i+1]*sc.y+sh.y, 0.f);
      const float y2 = fmaxf(xf[4*i+2]*sc.z+sh.z, 0.f);
      const float y3 = fmaxf(xf[4*i+3]*sc.w+sh.w, 0.f);
      uint2 yy; yy.x = pk2bf(y0,y1); yy.y = pk2bf(y2,y3);
      *reinterpret_cast<uint2*>(&ybuf[sr*LPAD + scb + i*4]) = yy;
    }
  }
  LDSFENCE();   // own stage rows committed (fc1 reads own rows only)

  const short8 ay0 = LD8(&ybuf[rowA*LPAD + ko]);
  const short8 ay1 = LD8(&ybuf[rowA*LPAD + 32 + ko]);

  // ---- fc1 (wave-row decomp, preloaded frags) ----
  f32x4 ac0={0.f,0.f,0.f,0.f}, ac1=ac0, ac2=ac0, ac3=ac0;
  ac0 = MFMA(ay0, f0a, ac0);  ac0 = MFMA(ay1, f0b, ac0);
  ac1 = MFMA(ay0, f1a, ac1);  ac1 = MFMA(ay1, f1b, ac1);
  ac2 = MFMA(ay0, f2a, ac2);  ac2 = MFMA(ay1, f2b, ac2);
  ac3 = MFMA(ay0, f3a, ac3);  ac3 = MFMA(ay1, f3b, ac3);
  {
    const float b0=fc1b[l15], b1=fc1b[16+l15], b2=fc1b[32+l15], b3=fc1b[48+l15];
    float tn0[4], tn1[4], tn2[4], tn3[4], mu[4], rs[4];
    #pragma unroll
    for (int j=0;j<4;j++){ tn0[j]=ac0[j]+b0; tn1[j]=ac1[j]+b1; tn2[j]=ac2[j]+b2; tn3[j]=ac3[j]+b3; }
    #pragma unroll
    for (int j=0;j<4;j++){
      float s = tn0[j]+tn1[j]+tn2[j]+tn3[j];
      s += __shfl_xor(s,1,16); s += __shfl_xor(s,2,16);
      s += __shfl_xor(s,4,16); s += __shfl_xor(s,8,16);
      mu[j] = s*(1.f/64.f);
    }
    #pragma unroll
    for (int j=0;j<4;j++){
      const float d0_=tn0[j]-mu[j], d1_=tn1[j]-mu[j], d2_=tn2[j]-mu[j], d3_=tn3[j]-mu[j];
      float v = d0_*d0_+d1_*d1_+d2_*d2_+d3_*d3_;
      v += __shfl_xor(v,1,16); v += __shfl_xor(v,2,16);
      v += __shfl_xor(v,4,16); v += __shfl_xor(v,8,16);
      rs[j] = 1.f/sqrtf(v*(1.f/64.f)+EPS_LN);
    }
    const float g0=lng[l15], g1=lng[16+l15], g2=lng[32+l15], g3=lng[48+l15];
    const float q0=lnb[l15], q1=lnb[16+l15], q2=lnb[32+l15], q3=lnb[48+l15];
    // LN into own stripe; antidep vs own ay reads is program order.
    #pragma unroll
    for (int j=0;j<4;j++){
      const int rr_ = rbase + kg*4 + j;
      ybuf[rr_*LPAD +      l15] = f2bf_hw(fmaxf((tn0[j]-mu[j])*rs[j]*g0+q0, 0.f));
      ybuf[rr_*LPAD + 16 + l15] = f2bf_hw(fmaxf((tn1[j]-mu[j])*rs[j]*g1+q1, 0.f));
      ybuf[rr_*LPAD + 32 + l15] = f2bf_hw(fmaxf((tn2[j]-mu[j])*rs[j]*g2+q2, 0.f));
      ybuf[rr_*LPAD + 48 + l15] = f2bf_hw(fmaxf((tn3[j]-mu[j])*rs[j]*g3+q3, 0.f));
    }
  }

  // ---- prefetch GRU (col gcol) weight frags + biases; land during barrier ----
  const int gcol = w*16 + l15;
  const ushort_t* gih = wb + WO_GIH;
  const ushort_t* ghh = wb + WO_GHH;
  const short8 wr0 = LD8(gih + (      gcol)*64 + ko);
  const short8 wr1 = LD8(gih + (      gcol)*64 + 32 + ko);
  const short8 wz0 = LD8(gih + ( 64 + gcol)*64 + ko);
  const short8 wz1 = LD8(gih + ( 64 + gcol)*64 + 32 + ko);
  const short8 wn0 = LD8(gih + (128 + gcol)*64 + ko);
  const short8 wn1 = LD8(gih + (128 + gcol)*64 + 32 + ko);
  const short8 vr0 = LD8(ghh + (      gcol)*64 + ko);
  const short8 vr1 = LD8(ghh + (      gcol)*64 + 32 + ko);
  const short8 vz0 = LD8(ghh + ( 64 + gcol)*64 + ko);
  const short8 vz1 = LD8(ghh + ( 64 + gcol)*64 + 32 + ko);
  const short8 vn0 = LD8(ghh + (128 + gcol)*64 + ko);
  const short8 vn1 = LD8(ghh + (128 + gcol)*64 + 32 + ko);
  const float bir=gbih[gcol],     bhr=gbhh[gcol];
  const float biz=gbih[64+gcol],  bhz=gbhh[64+gcol];
  const float bin_=gbih[128+gcol],bhn=gbhh[128+gcol];
  __syncthreads();   // ttl + all waves' stage visible; hraw DMA drained

  // ---- GRU: col-tile per wave, 4 row-groups; h bf16 kept in regs ----
  us4 hkeep[4];
  #pragma unroll
  for (int rg=0; rg<4; rg++){
    const int ra = rg*16 + l15;
    const short8 at0 = LD8(&ybuf[ra*LPAD + ko]);
    const short8 at1 = LD8(&ybuf[ra*LPAD + 32 + ko]);
    const short8 bh0 = hfrag(hraw, ra, 2*kg);      // cols ko..ko+7
    const short8 bh1 = hfrag(hraw, ra, 8+2*kg);    // cols 32+ko..32+ko+7
    f32x4 ar={0.f,0.f,0.f,0.f}, az=ar, an=ar, hn=ar;
    ar = MFMA(at0, wr0, ar);  ar = MFMA(at1, wr1, ar);
    ar = MFMA(bh0, vr0, ar);  ar = MFMA(bh1, vr1, ar);
    az = MFMA(at0, wz0, az);  az = MFMA(at1, wz1, az);
    az = MFMA(bh0, vz0, az);  az = MFMA(bh1, vz1, az);
    an = MFMA(at0, wn0, an);  an = MFMA(at1, wn1, an);
    hn = MFMA(bh0, vn0, hn);  hn = MFMA(bh1, vn1, hn);
    us4 hb4;
    #pragma unroll
    for (int j=0;j<4;j++){
      const int rloc = rg*16 + kg*4 + j;
      const size_t rg_ = (size_t)blockIdx.x*64 + rloc;
      const float rrg = fsig(ar[j]+bir+bhr);
      const float zzg = fsig(az[j]+biz+bhz);
      const float nng = ftanh(an[j]+bin_ + rrg*(hn[j]+bhn));
      const float hold = hraw[rloc*64 + ((((gcol>>2)^(rloc&15))<<2) + (gcol&3))];
      const float hv = (1.f-zzg)*nng + zzg*hold;
      out_h[rg_*64 + gcol] = hv;
      hb4[j] = f2bf_hw(hv);
    }
    hkeep[rg] = hb4;
  }

  // ---- head weight frags + bias: issue now, latency hides under the barriers ----
  const short8 ow0 = LD8(wb + WO_OUT + l15*64 + ko);
  const short8 ow1 = LD8(wb + WO_OUT + l15*64 + 32 + ko);
  const float ob = (l15 < 12) ? outb[l15] : 0.f;

  __syncthreads();   // all waves done reading ttl/hraw -> ybuf reusable as hvl
  #pragma unroll
  for (int rg=0; rg<4; rg++){
    #pragma unroll
    for (int j=0;j<4;j++)
      ybuf[(rg*16 + kg*4 + j)*LPAD + gcol] = hkeep[rg][j];
  }
  __syncthreads();   // hvl ready

  // ---- output head (wave-row decomp) ----
  const short8 av0 = LD8(&ybuf[rowA*LPAD + ko]);
  const short8 av1 = LD8(&ybuf[rowA*LPAD + 32 + ko]);
  f32x4 aa={0.f,0.f,0.f,0.f};
  aa = MFMA(av0, ow0, aa);
  aa = MFMA(av1, ow1, aa);
  if (l15 < 12){
    #pragma unroll
    for (int j=0;j<4;j++){
      const size_t rg_ = (size_t)blockIdx.x*64 + rbase + kg*4 + j;
      out_a[rg_*12 + l15] = aa[j] + ob;
    }
  }
}

extern "C" void kernel_launch(void* const* d_in, const int* in_sizes, int n_in,
                              void* d_out, int out_size, void* d_ws, size_t ws_size,
                              hipStream_t stream)
{
  (void)in_sizes; (void)n_in; (void)out_size; (void)ws_size;
  const float* inputs = (const float*)d_in[0];
  const float* hidden = (const float*)d_in[1];
  const int*   month  = (const int*)d_in[2];
  const float* jq     = (const float*)d_in[3];
  const float* wif    = (const float*)d_in[4];
  const float* whf    = (const float*)d_in[5];
  const float* bif    = (const float*)d_in[6];
  const float* bhf    = (const float*)d_in[7];
  const float* wib    = (const float*)d_in[8];
  const float* bib    = (const float*)d_in[10];
  const float* bhb    = (const float*)d_in[11];
  const float* fclw   = (const float*)d_in[12];
  const float* fclb   = (const float*)d_in[13];
  const float* projw  = (const float*)d_in[14];
  const float* convw  = (const float*)d_in[15];
  const float* convb  = (const float*)d_in[16];
  const float* bng    = (const float*)d_in[17];
  const float* bnb    = (const float*)d_in[18];
  const float* fc1w   = (const float*)d_in[19];
  const float* fc1b   = (const float*)d_in[20];
  const float* lng    = (const float*)d_in[21];
  const float* lnb    = (const float*)d_in[22];
  const float* gwih   = (const float*)d_in[23];
  const float* gwhh   = (const float*)d_in[24];
  const float* gbih   = (const float*)d_in[25];
  const float* gbhh   = (const float*)d_in[26];
  const float* outw   = (const float*)d_in[27];
  const float* outb   = (const float*)d_in[28];
  const float* lastw  = (const float*)d_in[29];

  float* ws  = (float*)d_ws;
  float* out = (float*)d_out;
  float* out_a  = out;
  float* out_h  = out + (size_t)NROWS*NACT;
  float* out_lg = out + (size_t)NROWS*(NACT+NHID);
  float* out_md = out + (size_t)NROWS*(NACT+NHID+4);
  ushort_t* wb = (ushort_t*)(ws + WS_WBF16);
  ushort_t* xgb = (ushort_t*)out_h;     // bf16 x_glb, block-local packed
  float* part1 = out_a;                 // [4096][64]
  float* part2 = out_a + (size_t)4096*64;

  hipLaunchKernelGGL(k1_lstm, dim3(NPROTO+4), dim3(256), 0, stream,
                     jq, wif, whf, bif, bhf, wib, bib, bhb,
                     fc1w, gwih, gwhh, outw, convw, wb, ws+WS_TH);
  hipLaunchKernelGGL(k2_proto, dim3(NPROTO), dim3(64), 0, stream,
                     ws+WS_TH, fclw, fclb, projw, convw, convb,
                     ws+WS_PV, ws+WS_PVSQ, ws+WS_CTAB, wb);
  hipLaunchKernelGGL(k3_mfma, dim3(NROWS/64), dim3(256), 0, stream,
                     inputs, month, ws+WS_PVSQ, ws+WS_CTAB, lastw, wb,
                     out_lg, out_md, xgb, part1, part2);
  hipLaunchKernelGGL(k4b_reduce, dim3(64), dim3(64), 0, stream,
                     part1, part2, (double*)(ws+WS_MID1), (double*)(ws+WS_MID2));
  hipLaunchKernelGGL(k5_finalize, dim3(1), dim3(64), 0, stream,
                     (const double*)(ws+WS_MID1), (const double*)(ws+WS_MID2),
                     bng, bnb, ws+WS_BNSC, ws+WS_BNSH);
  hipLaunchKernelGGL(k6_mfma, dim3(NROWS/64), dim3(256), 0, stream,
                     xgb, hidden, ws+WS_BNSC, ws+WS_BNSH, fc1b, lng, lnb,
                     gbih, gbhh, outb, wb, out_a, out_h);
}